// Round 1
// baseline (1924.062 us; speedup 1.0000x reference)
//
#include <hip/hip_runtime.h>
#include <cstdint>
#include <cstddef>

// Problem constants
constexpr int B_   = 4;
constexpr int SEQ  = 2048;
constexpr int E    = 1024;   // embed dim
constexpr int KVE  = 512;    // kv embed dim
constexpr int H    = 4;      // kv heads
constexpr int D    = 128;    // head dim
constexpr int ROWS = B_ * SEQ;   // 8192 tokens

// ---------------------------------------------------------------------------
// Weight stats: per-matrix sum(w) and sum(|w|) via block reduce + atomics
// ---------------------------------------------------------------------------
__global__ __launch_bounds__(256) void wstats_kernel(
    const float* __restrict__ w0, const float* __restrict__ w1,
    const float* __restrict__ w2, const float* __restrict__ w3,
    int n0, int n1, int n2, int n3, float* __restrict__ stats)
{
    int m = blockIdx.y;
    const float* w = (m == 0) ? w0 : (m == 1) ? w1 : (m == 2) ? w2 : w3;
    int n = (m == 0) ? n0 : (m == 1) ? n1 : (m == 2) ? n2 : n3;
    float s = 0.f, sa = 0.f;
    for (int i = blockIdx.x * 256 + threadIdx.x; i < n; i += gridDim.x * 256) {
        float x = w[i];
        s += x; sa += fabsf(x);
    }
#pragma unroll
    for (int o = 32; o; o >>= 1) { s += __shfl_xor(s, o); sa += __shfl_xor(sa, o); }
    __shared__ float ls[4], lsa[4];
    int lane = threadIdx.x & 63, wv = threadIdx.x >> 6;
    if (!lane) { ls[wv] = s; lsa[wv] = sa; }
    __syncthreads();
    if (!threadIdx.x) {
        atomicAdd(&stats[2 * m],     ls[0] + ls[1] + ls[2] + ls[3]);
        atomicAdd(&stats[2 * m + 1], lsa[0] + lsa[1] + lsa[2] + lsa[3]);
    }
}

// ---------------------------------------------------------------------------
// Weight ternary quant: wq = sign(w - mean(w)) as int8 (packed 4-wide)
// ---------------------------------------------------------------------------
__global__ __launch_bounds__(256) void wquant_kernel(
    const float* __restrict__ w0, const float* __restrict__ w1,
    const float* __restrict__ w2, const float* __restrict__ w3,
    int n0, int n1, int n2, int n3, const float* __restrict__ stats,
    int8_t* __restrict__ o0, int8_t* __restrict__ o1,
    int8_t* __restrict__ o2, int8_t* __restrict__ o3)
{
    int m = blockIdx.y;
    const float* w = (m == 0) ? w0 : (m == 1) ? w1 : (m == 2) ? w2 : w3;
    int n = (m == 0) ? n0 : (m == 1) ? n1 : (m == 2) ? n2 : n3;
    int8_t* o = (m == 0) ? o0 : (m == 1) ? o1 : (m == 2) ? o2 : o3;
    float e = stats[2 * m] / (float)n;
    int n4 = n >> 2;
    for (int i = blockIdx.x * 256 + threadIdx.x; i < n4; i += gridDim.x * 256) {
        float4 x = ((const float4*)w)[i];
        int q0 = (x.x > e) - (x.x < e);
        int q1 = (x.y > e) - (x.y < e);
        int q2 = (x.z > e) - (x.z < e);
        int q3 = (x.w > e) - (x.w < e);
        uint32_t pk = (uint32_t)(q0 & 0xff) | ((uint32_t)(q1 & 0xff) << 8) |
                      ((uint32_t)(q2 & 0xff) << 16) | ((uint32_t)(q3 & 0xff) << 24);
        *(uint32_t*)(o + ((size_t)i << 2)) = pk;
    }
}

// ---------------------------------------------------------------------------
// Activation quant: RMSNorm (weight=1) -> per-row int8 quant
// One block per row. C = 1024 (V=4) or 512 (V=2).
// ---------------------------------------------------------------------------
template <int C>
__global__ __launch_bounds__(256) void aquant_kernel(
    const float* __restrict__ x, int8_t* __restrict__ xq, float* __restrict__ dqv)
{
    constexpr int V = C / 256;
    int tid = threadIdx.x;
    size_t base = (size_t)blockIdx.x * C;
    float v[V];
    if constexpr (V == 4) {
        float4 t = *(const float4*)(x + base + tid * 4);
        v[0] = t.x; v[1] = t.y; v[2] = t.z; v[3] = t.w;
    } else {
        float2 t = *(const float2*)(x + base + tid * 2);
        v[0] = t.x; v[1] = t.y;
    }
    float ss = 0.f, am = 0.f;
#pragma unroll
    for (int i = 0; i < V; i++) { ss += v[i] * v[i]; am = fmaxf(am, fabsf(v[i])); }
#pragma unroll
    for (int o = 32; o; o >>= 1) { ss += __shfl_xor(ss, o); am = fmaxf(am, __shfl_xor(am, o)); }
    __shared__ float l1[4], l2[4];
    int lane = tid & 63, wv = tid >> 6;
    if (!lane) { l1[wv] = ss; l2[wv] = am; }
    __syncthreads();
    ss = l1[0] + l1[1] + l1[2] + l1[3];
    am = fmaxf(fmaxf(l2[0], l2[1]), fmaxf(l2[2], l2[3]));
    float rms = rsqrtf(ss * (1.0f / C) + 1e-6f);
    float amn = am * rms;                 // absmax of normalized row
    float cl  = fmaxf(amn, 1e-5f);
    float sc  = 127.0f / cl;
    float kf  = rms * sc;                 // x -> int domain in one mul
    uint32_t pk = 0;
#pragma unroll
    for (int i = 0; i < V; i++) {
        int q = (int)rintf(v[i] * kf);    // round-half-even == jnp.round
        q = max(-128, min(127, q));
        pk |= (uint32_t)(q & 0xff) << (8 * i);
    }
    if constexpr (V == 4) *(uint32_t*)(xq + base + tid * 4) = pk;
    else                  *(uint16_t*)(xq + base + tid * 2) = (uint16_t)pk;
    if (!tid) dqv[blockIdx.x] = cl * (1.0f / 127.0f);
}

// ---------------------------------------------------------------------------
// Int8 GEMM in fp32 (exact): C[r,o] = s_w * dq[r] * sum_k A8[r,k]*W8[o,k]
// 64x64 tile, BK=16, 256 threads, 4x4 per thread.
// ---------------------------------------------------------------------------
__global__ __launch_bounds__(256) void gemm_q8(
    const int8_t* __restrict__ A, const int8_t* __restrict__ W,
    const float* __restrict__ dqv, const float* __restrict__ stats, int sidx, float invn,
    float* __restrict__ Cmat, int O, int K)
{
    __shared__ float As[16][68];
    __shared__ float Ws[16][68];
    int tid = threadIdx.x;
    int r0 = blockIdx.y * 64, c0 = blockIdx.x * 64;
    int lr = tid >> 2, lk = (tid & 3) * 4;
    int rm = (tid & 15) * 4, on = (tid >> 4) * 4;
    float acc[4][4] = {};

    for (int kt = 0; kt < K; kt += 16) {
        int32_t wa = *(const int32_t*)(A + (size_t)(r0 + lr) * K + kt + lk);
        int32_t wb = *(const int32_t*)(W + (size_t)(c0 + lr) * K + kt + lk);
        As[lk + 0][lr] = (float)(int8_t)(wa);
        As[lk + 1][lr] = (float)(int8_t)(wa >> 8);
        As[lk + 2][lr] = (float)(int8_t)(wa >> 16);
        As[lk + 3][lr] = (float)(wa >> 24);
        Ws[lk + 0][lr] = (float)(int8_t)(wb);
        Ws[lk + 1][lr] = (float)(int8_t)(wb >> 8);
        Ws[lk + 2][lr] = (float)(int8_t)(wb >> 16);
        Ws[lk + 3][lr] = (float)(wb >> 24);
        __syncthreads();
#pragma unroll
        for (int kk = 0; kk < 16; kk++) {
            float4 a = *(const float4*)&As[kk][rm];
            float4 b = *(const float4*)&Ws[kk][on];
            acc[0][0] += a.x * b.x; acc[0][1] += a.x * b.y; acc[0][2] += a.x * b.z; acc[0][3] += a.x * b.w;
            acc[1][0] += a.y * b.x; acc[1][1] += a.y * b.y; acc[1][2] += a.y * b.z; acc[1][3] += a.y * b.w;
            acc[2][0] += a.z * b.x; acc[2][1] += a.z * b.y; acc[2][2] += a.z * b.z; acc[2][3] += a.z * b.w;
            acc[3][0] += a.w * b.x; acc[3][1] += a.w * b.y; acc[3][2] += a.w * b.z; acc[3][3] += a.w * b.w;
        }
        __syncthreads();
    }
    float sw = stats[2 * sidx + 1] * invn;  // mean|w|
#pragma unroll
    for (int i = 0; i < 4; i++) {
        int r = r0 + rm + i;
        float scv = sw * dqv[r];
        float4 outv = { acc[i][0] * scv, acc[i][1] * scv, acc[i][2] * scv, acc[i][3] * scv };
        *(float4*)&Cmat[(size_t)r * O + c0 + on] = outv;
    }
}

// ---------------------------------------------------------------------------
// Fused flash attention (fp32). Block = (16 q-rows, kv-head h, batch b).
// qs = (q_head(2h) + q_head(2h+1)) / 128 folded.  Online softmax per row.
// K/V LDS tiles use XOR chunk swizzle for conflict-free float4 reads.
// ---------------------------------------------------------------------------
__global__ __launch_bounds__(256) void attn_kernel(
    const float* __restrict__ qbuf, const float* __restrict__ kbuf,
    const float* __restrict__ vbuf, float* __restrict__ xbuf)
{
    constexpr int TQ = 16, TS = 64;
    __shared__ float qs[TQ][D];   // logical layout (broadcast reads)
    __shared__ float kv[TS][D];   // xor-swizzled chunks
    __shared__ float P[TQ][TS];
    int tid = threadIdx.x, lane = tid & 63, wave = tid >> 6;
    int nt = blockIdx.x, h = blockIdx.y, b = blockIdx.z;

    // load q tile: sum the two grouped q heads, fold 1/(scale^2) = 1/128
    for (int i = tid; i < TQ * D / 4; i += 256) {
        int n = i >> 5, c = i & 31;
        const float4* r = (const float4*)(qbuf + ((size_t)(b * SEQ + nt * TQ + n)) * E + h * (2 * D));
        float4 a = r[c], bb = r[32 + c];
        float4 qv;
        qv.x = (a.x + bb.x) * (1.0f / 128.0f);
        qv.y = (a.y + bb.y) * (1.0f / 128.0f);
        qv.z = (a.z + bb.z) * (1.0f / 128.0f);
        qv.w = (a.w + bb.w) * (1.0f / 128.0f);
        *(float4*)&qs[n][c << 2] = qv;
    }

    float o[8] = {0, 0, 0, 0, 0, 0, 0, 0};
    float m0 = -__builtin_inff(), m1 = m0, m2 = m0, m3 = m0;
    float l0 = 0.f, l1 = 0.f, l2 = 0.f, l3 = 0.f;
    int r0 = wave * 4;
    int nrow = r0 + (lane >> 4);
    int dg = lane & 15;
    int swz = lane & 7;

    for (int st = 0; st < SEQ / TS; ++st) {
        __syncthreads();  // protect kv/P from previous iteration's readers
        size_t kbase = ((size_t)(b * SEQ + st * TS)) * KVE + h * D;
        for (int i = tid; i < TS * D / 4; i += 256) {
            int s = i >> 5, c = i & 31;
            float4 t = *(const float4*)(kbuf + kbase + (size_t)s * KVE + (c << 2));
            *(float4*)&kv[s][((c ^ (s & 7)) << 2)] = t;
        }
        __syncthreads();
        // scores: wave w handles rows 4w..4w+3, column s = lane
        float a0 = 0.f, a1 = 0.f, a2 = 0.f, a3 = 0.f;
#pragma unroll
        for (int c = 0; c < 32; c++) {
            float4 kk = *(const float4*)&kv[lane][((c ^ swz) << 2)];
            float4 qa = *(const float4*)&qs[r0 + 0][c << 2];
            float4 qb = *(const float4*)&qs[r0 + 1][c << 2];
            float4 qc = *(const float4*)&qs[r0 + 2][c << 2];
            float4 qd = *(const float4*)&qs[r0 + 3][c << 2];
            a0 += qa.x * kk.x + qa.y * kk.y + qa.z * kk.z + qa.w * kk.w;
            a1 += qb.x * kk.x + qb.y * kk.y + qb.z * kk.z + qb.w * kk.w;
            a2 += qc.x * kk.x + qc.y * kk.y + qc.z * kk.z + qc.w * kk.w;
            a3 += qd.x * kk.x + qd.y * kk.y + qd.z * kk.z + qd.w * kk.w;
        }
        // online softmax (per wave; each wave owns its 4 rows entirely)
        float t0 = a0, t1 = a1, t2 = a2, t3 = a3;
#pragma unroll
        for (int ofs = 32; ofs; ofs >>= 1) {
            t0 = fmaxf(t0, __shfl_xor(t0, ofs));
            t1 = fmaxf(t1, __shfl_xor(t1, ofs));
            t2 = fmaxf(t2, __shfl_xor(t2, ofs));
            t3 = fmaxf(t3, __shfl_xor(t3, ofs));
        }
        float n0 = fmaxf(m0, t0), n1 = fmaxf(m1, t1), n2 = fmaxf(m2, t2), n3 = fmaxf(m3, t3);
        float al0 = __expf(m0 - n0), al1 = __expf(m1 - n1), al2 = __expf(m2 - n2), al3 = __expf(m3 - n3);
        float p0 = __expf(a0 - n0), p1 = __expf(a1 - n1), p2 = __expf(a2 - n2), p3 = __expf(a3 - n3);
        P[r0 + 0][lane] = p0; P[r0 + 1][lane] = p1; P[r0 + 2][lane] = p2; P[r0 + 3][lane] = p3;
        float s0 = p0, s1 = p1, s2 = p2, s3 = p3;
#pragma unroll
        for (int ofs = 32; ofs; ofs >>= 1) {
            s0 += __shfl_xor(s0, ofs); s1 += __shfl_xor(s1, ofs);
            s2 += __shfl_xor(s2, ofs); s3 += __shfl_xor(s3, ofs);
        }
        l0 = l0 * al0 + s0; l1 = l1 * al1 + s1; l2 = l2 * al2 + s2; l3 = l3 * al3 + s3;
        m0 = n0; m1 = n1; m2 = n2; m3 = n3;
        int rs = lane >> 4;
        float arow = rs == 0 ? al0 : rs == 1 ? al1 : rs == 2 ? al2 : al3;
#pragma unroll
        for (int j = 0; j < 8; j++) o[j] *= arow;
        __syncthreads();   // all kv(K) reads + P writes done
        // stage V (overwrite kv)
        for (int i = tid; i < TS * D / 4; i += 256) {
            int s = i >> 5, c = i & 31;
            float4 t = *(const float4*)(vbuf + kbase + (size_t)s * KVE + (c << 2));
            *(float4*)&kv[s][((c ^ (s & 7)) << 2)] = t;
        }
        __syncthreads();
        // PV: thread owns O[nrow][dg*4..+3] and O[nrow][64+dg*4..+3]
#pragma unroll 8
        for (int s = 0; s < TS; s++) {
            float pp = P[nrow][s];
            int sw2 = s & 7;
            float4 va = *(const float4*)&kv[s][((dg ^ sw2) << 2)];
            float4 vb = *(const float4*)&kv[s][(((dg + 16) ^ sw2) << 2)];
            o[0] += pp * va.x; o[1] += pp * va.y; o[2] += pp * va.z; o[3] += pp * va.w;
            o[4] += pp * vb.x; o[5] += pp * vb.y; o[6] += pp * vb.z; o[7] += pp * vb.w;
        }
    }
    int rs = lane >> 4;
    float lrow = rs == 0 ? l0 : rs == 1 ? l1 : rs == 2 ? l2 : l3;
    float inv = 1.0f / lrow;
    size_t ob = ((size_t)(b * SEQ + nt * TQ + nrow)) * KVE + h * D;
    float4 w0 = { o[0] * inv, o[1] * inv, o[2] * inv, o[3] * inv };
    float4 w1 = { o[4] * inv, o[5] * inv, o[6] * inv, o[7] * inv };
    *(float4*)(xbuf + ob + (dg << 2)) = w0;
    *(float4*)(xbuf + ob + 64 + (dg << 2)) = w1;
}

// ---------------------------------------------------------------------------
// LayerNorm(gamma,beta) + RMSNorm + int8 quant, one block per row (C=512)
// ---------------------------------------------------------------------------
__global__ __launch_bounds__(256) void lnquant_kernel(
    const float* __restrict__ x, const float* __restrict__ gamma,
    const float* __restrict__ beta, int8_t* __restrict__ xq, float* __restrict__ dqv)
{
    int row = blockIdx.x, tid = threadIdx.x;
    float2 v = *(const float2*)(x + (size_t)row * KVE + tid * 2);
    float s = v.x + v.y, ss = v.x * v.x + v.y * v.y;
#pragma unroll
    for (int o = 32; o; o >>= 1) { s += __shfl_xor(s, o); ss += __shfl_xor(ss, o); }
    __shared__ float r1[4], r2[4];
    int lane = tid & 63, wv = tid >> 6;
    if (!lane) { r1[wv] = s; r2[wv] = ss; }
    __syncthreads();
    float stot = r1[0] + r1[1] + r1[2] + r1[3];
    float sstot = r2[0] + r2[1] + r2[2] + r2[3];
    float mu = stot * (1.0f / KVE);
    float var = fmaxf(sstot * (1.0f / KVE) - mu * mu, 0.0f);
    float inv = rsqrtf(var + 1e-5f);
    float2 g = *(const float2*)(gamma + tid * 2);
    float2 be = *(const float2*)(beta + tid * 2);
    float y0 = (v.x - mu) * inv * g.x + be.x;
    float y1 = (v.y - mu) * inv * g.y + be.y;
    float sy = y0 * y0 + y1 * y1;
    float am = fmaxf(fabsf(y0), fabsf(y1));
#pragma unroll
    for (int o = 32; o; o >>= 1) { sy += __shfl_xor(sy, o); am = fmaxf(am, __shfl_xor(am, o)); }
    __syncthreads();   // r1/r2 reuse
    if (!lane) { r1[wv] = sy; r2[wv] = am; }
    __syncthreads();
    float sytot = r1[0] + r1[1] + r1[2] + r1[3];
    float amax = fmaxf(fmaxf(r2[0], r2[1]), fmaxf(r2[2], r2[3]));
    float rms = rsqrtf(sytot * (1.0f / KVE) + 1e-6f);
    float amn = amax * rms;
    float cl = fmaxf(amn, 1e-5f);
    float sc = 127.0f / cl;
    float kf = rms * sc;
    int q0 = max(-128, min(127, (int)rintf(y0 * kf)));
    int q1 = max(-128, min(127, (int)rintf(y1 * kf)));
    uint16_t pk = (uint16_t)((q0 & 0xff) | ((q1 & 0xff) << 8));
    *(uint16_t*)(xq + (size_t)row * KVE + tid * 2) = pk;
    if (!tid) dqv[row] = cl * (1.0f / 127.0f);
}

// ---------------------------------------------------------------------------
extern "C" void kernel_launch(void* const* d_in, const int* in_sizes, int n_in,
                              void* d_out, int out_size, void* d_ws, size_t ws_size,
                              hipStream_t stream)
{
    const float* query = (const float*)d_in[0];
    const float* key   = (const float*)d_in[1];
    const float* value = (const float*)d_in[2];
    const float* q_w   = (const float*)d_in[3];
    const float* k_w   = (const float*)d_in[4];
    const float* v_w   = (const float*)d_in[5];
    const float* out_w = (const float*)d_in[6];
    const float* ln_g  = (const float*)d_in[7];
    const float* ln_b  = (const float*)d_in[8];
    float* out = (float*)d_out;

    // workspace carve (all 256-aligned)
    char* p = (char*)d_ws;
    float*  stats = (float*)p;  p += 256;
    int8_t* wq_q = (int8_t*)p;  p += 1024 * 1024;
    int8_t* wq_k = (int8_t*)p;  p += 512 * 1024;
    int8_t* wq_v = (int8_t*)p;  p += 512 * 1024;
    int8_t* wq_o = (int8_t*)p;  p += 1024 * 512;
    int8_t* xq   = (int8_t*)p;  p += (size_t)ROWS * 1024;
    float*  dqv  = (float*)p;   p += (size_t)ROWS * 4;
    float*  qb   = (float*)p;   p += (size_t)ROWS * E * 4;
    float*  kb   = (float*)p;   p += (size_t)ROWS * KVE * 4;
    float*  vb   = (float*)p;   p += (size_t)ROWS * KVE * 4;
    float*  xb   = (float*)p;   p += (size_t)ROWS * KVE * 4;
    if ((size_t)(p - (char*)d_ws) > ws_size) return;  // fail loudly via mismatch

    dim3 blk(256);
    hipMemsetAsync(stats, 0, 256, stream);
    wstats_kernel<<<dim3(32, 4), blk, 0, stream>>>(q_w, k_w, v_w, out_w,
        1024 * 1024, 512 * 1024, 512 * 1024, 1024 * 512, stats);
    wquant_kernel<<<dim3(64, 4), blk, 0, stream>>>(q_w, k_w, v_w, out_w,
        1024 * 1024, 512 * 1024, 512 * 1024, 1024 * 512, stats, wq_q, wq_k, wq_v, wq_o);

    aquant_kernel<1024><<<ROWS, blk, 0, stream>>>(query, xq, dqv);
    gemm_q8<<<dim3(16, 128), blk, 0, stream>>>(xq, wq_q, dqv, stats, 0,
        1.0f / (1024.0f * 1024.0f), qb, 1024, 1024);
    aquant_kernel<1024><<<ROWS, blk, 0, stream>>>(key, xq, dqv);
    gemm_q8<<<dim3(8, 128), blk, 0, stream>>>(xq, wq_k, dqv, stats, 1,
        1.0f / (512.0f * 1024.0f), kb, 512, 1024);
    aquant_kernel<1024><<<ROWS, blk, 0, stream>>>(value, xq, dqv);
    gemm_q8<<<dim3(8, 128), blk, 0, stream>>>(xq, wq_v, dqv, stats, 2,
        1.0f / (512.0f * 1024.0f), vb, 512, 1024);

    attn_kernel<<<dim3(SEQ / 16, H, B_), blk, 0, stream>>>(qb, kb, vb, xb);

    lnquant_kernel<<<ROWS, blk, 0, stream>>>(xb, ln_g, ln_b, xq, dqv);
    gemm_q8<<<dim3(16, 128), blk, 0, stream>>>(xq, wq_o, dqv, stats, 3,
        1.0f / (1024.0f * 512.0f), out, 1024, 512);
}

// Round 2
// 435.913 us; speedup vs baseline: 4.4139x; 4.4139x over previous
//
#include <hip/hip_runtime.h>
#include <cstdint>
#include <cstddef>

// Problem constants
constexpr int B_   = 4;
constexpr int SEQ  = 2048;
constexpr int E    = 1024;   // embed dim
constexpr int KVE  = 512;    // kv embed dim
constexpr int H    = 4;      // kv heads
constexpr int ROWS = B_ * SEQ;   // 8192 tokens

typedef short short8  __attribute__((ext_vector_type(8)));
typedef short short4v __attribute__((ext_vector_type(4)));
typedef float floatx4 __attribute__((ext_vector_type(4)));

__device__ inline short f2bf(float f) {   // RNE float->bf16
    uint32_t u = __builtin_bit_cast(uint32_t, f);
    u = (u + 0x7fff + ((u >> 16) & 1)) >> 16;
    return (short)u;
}
__device__ inline float bf2f(short s) {
    return __builtin_bit_cast(float, (uint32_t)(uint16_t)s << 16);
}
__device__ inline void gl_lds16(const void* g, void* l) {
    __builtin_amdgcn_global_load_lds(
        (const __attribute__((address_space(1))) unsigned int*)g,
        (__attribute__((address_space(3))) unsigned int*)l, 16, 0, 0);
}

// ---------------------------------------------------------------------------
// Weight stats: per-matrix sum(w) and sum(|w|)
// ---------------------------------------------------------------------------
__global__ __launch_bounds__(256) void wstats_kernel(
    const float* __restrict__ w0, const float* __restrict__ w1,
    const float* __restrict__ w2, const float* __restrict__ w3,
    int n0, int n1, int n2, int n3, float* __restrict__ stats)
{
    int m = blockIdx.y;
    const float* w = (m == 0) ? w0 : (m == 1) ? w1 : (m == 2) ? w2 : w3;
    int n = (m == 0) ? n0 : (m == 1) ? n1 : (m == 2) ? n2 : n3;
    float s = 0.f, sa = 0.f;
    for (int i = blockIdx.x * 256 + threadIdx.x; i < n; i += gridDim.x * 256) {
        float x = w[i];
        s += x; sa += fabsf(x);
    }
#pragma unroll
    for (int o = 32; o; o >>= 1) { s += __shfl_xor(s, o); sa += __shfl_xor(sa, o); }
    __shared__ float ls[4], lsa[4];
    int lane = threadIdx.x & 63, wv = threadIdx.x >> 6;
    if (!lane) { ls[wv] = s; lsa[wv] = sa; }
    __syncthreads();
    if (!threadIdx.x) {
        atomicAdd(&stats[2 * m],     ls[0] + ls[1] + ls[2] + ls[3]);
        atomicAdd(&stats[2 * m + 1], lsa[0] + lsa[1] + lsa[2] + lsa[3]);
    }
}

// ---------------------------------------------------------------------------
// Weight ternary quant -> bf16 {-1,0,+1}
// ---------------------------------------------------------------------------
__global__ __launch_bounds__(256) void wquant_kernel(
    const float* __restrict__ w0, const float* __restrict__ w1,
    const float* __restrict__ w2, const float* __restrict__ w3,
    int n0, int n1, int n2, int n3, const float* __restrict__ stats,
    short* __restrict__ o0, short* __restrict__ o1,
    short* __restrict__ o2, short* __restrict__ o3)
{
    int m = blockIdx.y;
    const float* w = (m == 0) ? w0 : (m == 1) ? w1 : (m == 2) ? w2 : w3;
    int n = (m == 0) ? n0 : (m == 1) ? n1 : (m == 2) ? n2 : n3;
    short* o = (m == 0) ? o0 : (m == 1) ? o1 : (m == 2) ? o2 : o3;
    float e = stats[2 * m] / (float)n;
    int n4 = n >> 2;
    for (int i = blockIdx.x * 256 + threadIdx.x; i < n4; i += gridDim.x * 256) {
        float4 x = ((const float4*)w)[i];
        short4v q;
        q.x = (x.x > e) ? (short)0x3F80 : (x.x < e) ? (short)0xBF80 : (short)0;
        q.y = (x.y > e) ? (short)0x3F80 : (x.y < e) ? (short)0xBF80 : (short)0;
        q.z = (x.z > e) ? (short)0x3F80 : (x.z < e) ? (short)0xBF80 : (short)0;
        q.w = (x.w > e) ? (short)0x3F80 : (x.w < e) ? (short)0xBF80 : (short)0;
        *(short4v*)(o + ((size_t)i << 2)) = q;
    }
}

// ---------------------------------------------------------------------------
// Activation quant: RMSNorm -> int8 values stored as exact bf16
// ---------------------------------------------------------------------------
template <int C>
__global__ __launch_bounds__(256) void aquant_kernel(
    const float* __restrict__ x, short* __restrict__ xq, float* __restrict__ dqv)
{
    constexpr int V = C / 256;
    int tid = threadIdx.x;
    size_t base = (size_t)blockIdx.x * C;
    float v[V];
    if constexpr (V == 4) {
        float4 t = *(const float4*)(x + base + tid * 4);
        v[0] = t.x; v[1] = t.y; v[2] = t.z; v[3] = t.w;
    } else {
        float2 t = *(const float2*)(x + base + tid * 2);
        v[0] = t.x; v[1] = t.y;
    }
    float ss = 0.f, am = 0.f;
#pragma unroll
    for (int i = 0; i < V; i++) { ss += v[i] * v[i]; am = fmaxf(am, fabsf(v[i])); }
#pragma unroll
    for (int o = 32; o; o >>= 1) { ss += __shfl_xor(ss, o); am = fmaxf(am, __shfl_xor(am, o)); }
    __shared__ float l1[4], l2[4];
    int lane = tid & 63, wv = tid >> 6;
    if (!lane) { l1[wv] = ss; l2[wv] = am; }
    __syncthreads();
    ss = l1[0] + l1[1] + l1[2] + l1[3];
    am = fmaxf(fmaxf(l2[0], l2[1]), fmaxf(l2[2], l2[3]));
    float rms = rsqrtf(ss * (1.0f / C) + 1e-6f);
    float cl  = fmaxf(am * rms, 1e-5f);
    float kf  = rms * (127.0f / cl);
    short qs[V];
#pragma unroll
    for (int i = 0; i < V; i++) {
        int q = (int)rintf(v[i] * kf);
        q = max(-128, min(127, q));
        qs[i] = f2bf((float)q);     // exact
    }
    if constexpr (V == 4) {
        short4v pk = { qs[0], qs[1], qs[2], qs[3] };
        *(short4v*)(xq + base + tid * 4) = pk;
    } else {
        *(short*)(xq + base + tid * 2) = qs[0];
        *(short*)(xq + base + tid * 2 + 1) = qs[1];
    }
    if (!tid) dqv[blockIdx.x] = cl * (1.0f / 127.0f);
}

// ---------------------------------------------------------------------------
// bf16 MFMA GEMM (bit-exact: integer-valued bf16 inputs, fp32 acc)
// 128x128 tile, BK=32, 4 waves (2x2 of 64x64), global_load_lds w16,
// XOR-chunk swizzle (chunk pos = k_chunk ^ (row&3)) for bank balance.
// ---------------------------------------------------------------------------
template <bool F32OUT>
__global__ __launch_bounds__(256) void gemm_bf16(
    const short* __restrict__ A, const short* __restrict__ W,
    const float* __restrict__ dqv, const float* __restrict__ stats, int sidx, float invn,
    void* __restrict__ Cout, int O, int K)
{
    __shared__ short As[128 * 32];
    __shared__ short Ws[128 * 32];
    int tid = threadIdx.x;
    int w = tid >> 6, lane = tid & 63;
    int quad = lane >> 4, l15 = lane & 15;
    size_t row0 = (size_t)blockIdx.y * 128;
    size_t c0 = (size_t)blockIdx.x * 128;
    int mbase = (w & 1) * 64, nbase = (w >> 1) * 64;

    floatx4 acc[4][4];
#pragma unroll
    for (int i = 0; i < 4; i++)
#pragma unroll
        for (int j = 0; j < 4; j++) acc[i][j] = (floatx4){0.f, 0.f, 0.f, 0.f};

    // chunk c: LDS pos c (row=c>>2, pos=c&3) holds global k-chunk (pos^(row&3))
    int cA0 = tid, cA1 = tid + 256;
    int rA0 = cA0 >> 2, gA0 = (cA0 & 3) ^ (rA0 & 3);
    int rA1 = cA1 >> 2, gA1 = (cA1 & 3) ^ (rA1 & 3);
    const short* Ag0 = A + (row0 + rA0) * K + gA0 * 8;
    const short* Ag1 = A + (row0 + rA1) * K + gA1 * 8;
    const short* Wg0 = W + (c0 + rA0) * K + gA0 * 8;
    const short* Wg1 = W + (c0 + rA1) * K + gA1 * 8;
    short* lA0 = As + cA0 * 8;  short* lA1 = As + cA1 * 8;
    short* lW0 = Ws + cA0 * 8;  short* lW1 = Ws + cA1 * 8;

    for (int kt = 0; kt < K; kt += 32) {
        __syncthreads();
        gl_lds16(Ag0 + kt, lA0);
        gl_lds16(Ag1 + kt, lA1);
        gl_lds16(Wg0 + kt, lW0);
        gl_lds16(Wg1 + kt, lW1);
        __syncthreads();
        short8 af[4], bfr[4];
#pragma unroll
        for (int mt = 0; mt < 4; mt++) {
            int row = mbase + mt * 16 + l15;
            int pos = quad ^ (row & 3);
            af[mt] = *(const short8*)(As + row * 32 + pos * 8);
        }
#pragma unroll
        for (int nt = 0; nt < 4; nt++) {
            int row = nbase + nt * 16 + l15;
            int pos = quad ^ (row & 3);
            bfr[nt] = *(const short8*)(Ws + row * 32 + pos * 8);
        }
#pragma unroll
        for (int mt = 0; mt < 4; mt++)
#pragma unroll
            for (int nt = 0; nt < 4; nt++)
                acc[mt][nt] = __builtin_amdgcn_mfma_f32_16x16x32_bf16(
                    af[mt], bfr[nt], acc[mt][nt], 0, 0, 0);
    }

    float sw = stats[2 * sidx + 1] * invn;
#pragma unroll
    for (int mt = 0; mt < 4; mt++) {
#pragma unroll
        for (int r = 0; r < 4; r++) {
            size_t grow = row0 + mbase + mt * 16 + quad * 4 + r;
            float scv = sw * dqv[grow];
#pragma unroll
            for (int nt = 0; nt < 4; nt++) {
                size_t gcol = c0 + nbase + nt * 16 + l15;
                float v = acc[mt][nt][r] * scv;
                if constexpr (F32OUT) ((float*)Cout)[grow * O + gcol] = v;
                else                  ((short*)Cout)[grow * O + gcol] = f2bf(v);
            }
        }
    }
}

// ---------------------------------------------------------------------------
// MFMA flash attention (bf16 in, fp32 softmax/acc).
// Block: 64 q-rows x (kv-head h, batch b). 4 waves, wave owns 16 q-rows.
// S-tile = 64 kv rows. Q,K row-major bf16 (pad->136), V transposed (pad->72),
// P via LDS round-trip (C-layout -> A-layout).
// ---------------------------------------------------------------------------
__global__ __launch_bounds__(256, 2) void attn_mfma(
    const short* __restrict__ qb, const short* __restrict__ kb,
    const short* __restrict__ vb, float* __restrict__ xb)
{
    __shared__ short Qs[64][136];
    __shared__ short Ks[64][136];
    __shared__ short Vt[128][72];
    __shared__ short Ps[64][72];
    int tid = threadIdx.x;
    int w = tid >> 6, lane = tid & 63, quad = lane >> 4, l15 = lane & 15;
    int blk = blockIdx.x, h = blockIdx.y, b = blockIdx.z;
    size_t qrow0 = (size_t)(b * SEQ + blk * 64);

    // stage Q once: sum grouped head pair, fold 1/(scale^2) = 1/128
    {
        int n = tid >> 2, c4 = tid & 3;
        const short* src = qb + (qrow0 + n) * E + h * 256 + c4 * 32;
#pragma unroll
        for (int j = 0; j < 4; j++) {
            short8 a  = *(const short8*)(src + j * 8);
            short8 b2 = *(const short8*)(src + 128 + j * 8);
            short8 o;
#pragma unroll
            for (int e = 0; e < 8; e++)
                o[e] = f2bf((bf2f(a[e]) + bf2f(b2[e])) * (1.0f / 128.0f));
            *(short8*)&Qs[n][c4 * 32 + j * 8] = o;
        }
    }
    __syncthreads();
    short8 qa[4];
#pragma unroll
    for (int ks = 0; ks < 4; ks++)
        qa[ks] = *(const short8*)&Qs[w * 16 + l15][ks * 32 + quad * 8];

    floatx4 oacc[8];
#pragma unroll
    for (int i = 0; i < 8; i++) oacc[i] = (floatx4){0.f, 0.f, 0.f, 0.f};
    float m_r[4] = {-1e30f, -1e30f, -1e30f, -1e30f};
    float l_r[4] = {0.f, 0.f, 0.f, 0.f};

    for (int st = 0; st < SEQ / 64; st++) {
        __syncthreads();   // prev iter's PV reads of Ks/Vt done
        size_t srow0 = (size_t)(b * SEQ + st * 64);
        {   // stage K tile (row-major copy)
            int s = tid >> 2, c4 = tid & 3;
            const short* src = kb + (srow0 + s) * KVE + h * 128 + c4 * 32;
#pragma unroll
            for (int j = 0; j < 4; j++)
                *(short8*)&Ks[s][c4 * 32 + j * 8] = *(const short8*)(src + j * 8);
        }
        {   // stage V transposed
            int sq = (tid & 15) * 4, dc = tid >> 4;   // dc: 16 chunks of 8 d
            const short* src = vb + (srow0 + sq) * KVE + h * 128 + dc * 8;
            short8 r0 = *(const short8*)(src);
            short8 r1 = *(const short8*)(src + KVE);
            short8 r2 = *(const short8*)(src + 2 * KVE);
            short8 r3 = *(const short8*)(src + 3 * KVE);
#pragma unroll
            for (int i = 0; i < 8; i++) {
                short4v vv = { r0[i], r1[i], r2[i], r3[i] };
                *(short4v*)&Vt[dc * 8 + i][sq] = vv;
            }
        }
        __syncthreads();
        // QK^T: wave's 16 q-rows x 64 s-cols
        floatx4 sc[4];
#pragma unroll
        for (int nt = 0; nt < 4; nt++) {
            floatx4 a = (floatx4){0.f, 0.f, 0.f, 0.f};
#pragma unroll
            for (int ks = 0; ks < 4; ks++) {
                short8 kf = *(const short8*)&Ks[nt * 16 + l15][ks * 32 + quad * 8];
                a = __builtin_amdgcn_mfma_f32_16x16x32_bf16(qa[ks], kf, a, 0, 0, 0);
            }
            sc[nt] = a;
        }
        // online softmax: row = quad*4 + r, cols spread over 16-lane quad group
        float alpha[4];
#pragma unroll
        for (int r = 0; r < 4; r++) {
            float mx = fmaxf(fmaxf(sc[0][r], sc[1][r]), fmaxf(sc[2][r], sc[3][r]));
#pragma unroll
            for (int o = 1; o < 16; o <<= 1) mx = fmaxf(mx, __shfl_xor(mx, o));
            float nm = fmaxf(m_r[r], mx);
            alpha[r] = __expf(m_r[r] - nm);
            m_r[r] = nm;
            float rs = 0.f;
#pragma unroll
            for (int nt = 0; nt < 4; nt++) {
                float p = __expf(sc[nt][r] - nm);
                sc[nt][r] = p;
                rs += p;
            }
#pragma unroll
            for (int o = 1; o < 16; o <<= 1) rs += __shfl_xor(rs, o);
            l_r[r] = l_r[r] * alpha[r] + rs;
        }
        // P -> LDS (own wave's rows only; same-wave write->read needs no barrier)
#pragma unroll
        for (int nt = 0; nt < 4; nt++)
#pragma unroll
            for (int r = 0; r < 4; r++)
                Ps[w * 16 + quad * 4 + r][nt * 16 + l15] = f2bf(sc[nt][r]);
        // rescale O
#pragma unroll
        for (int nt = 0; nt < 8; nt++)
#pragma unroll
            for (int r = 0; r < 4; r++) oacc[nt][r] *= alpha[r];
        // PV: A = P (own rows), B = Vt (staged before the QK barrier)
        short8 pa0 = *(const short8*)&Ps[w * 16 + l15][quad * 8];
        short8 pa1 = *(const short8*)&Ps[w * 16 + l15][32 + quad * 8];
#pragma unroll
        for (int nt = 0; nt < 8; nt++) {
            short8 vf0 = *(const short8*)&Vt[nt * 16 + l15][quad * 8];
            short8 vf1 = *(const short8*)&Vt[nt * 16 + l15][32 + quad * 8];
            oacc[nt] = __builtin_amdgcn_mfma_f32_16x16x32_bf16(pa0, vf0, oacc[nt], 0, 0, 0);
            oacc[nt] = __builtin_amdgcn_mfma_f32_16x16x32_bf16(pa1, vf1, oacc[nt], 0, 0, 0);
        }
    }
#pragma unroll
    for (int r = 0; r < 4; r++) {
        float inv = 1.0f / l_r[r];
        size_t grow = qrow0 + w * 16 + quad * 4 + r;
        float* dst = xb + grow * KVE + h * 128;
#pragma unroll
        for (int nt = 0; nt < 8; nt++)
            dst[nt * 16 + l15] = oacc[nt][r] * inv;
    }
}

// ---------------------------------------------------------------------------
// LayerNorm + RMSNorm + int8 quant (stored as exact bf16), one block per row
// ---------------------------------------------------------------------------
__global__ __launch_bounds__(256) void lnquant_kernel(
    const float* __restrict__ x, const float* __restrict__ gamma,
    const float* __restrict__ beta, short* __restrict__ xq, float* __restrict__ dqv)
{
    int row = blockIdx.x, tid = threadIdx.x;
    float2 v = *(const float2*)(x + (size_t)row * KVE + tid * 2);
    float s = v.x + v.y, ss = v.x * v.x + v.y * v.y;
#pragma unroll
    for (int o = 32; o; o >>= 1) { s += __shfl_xor(s, o); ss += __shfl_xor(ss, o); }
    __shared__ float r1[4], r2[4];
    int lane = tid & 63, wv = tid >> 6;
    if (!lane) { r1[wv] = s; r2[wv] = ss; }
    __syncthreads();
    float stot = r1[0] + r1[1] + r1[2] + r1[3];
    float sstot = r2[0] + r2[1] + r2[2] + r2[3];
    float mu = stot * (1.0f / KVE);
    float var = fmaxf(sstot * (1.0f / KVE) - mu * mu, 0.0f);
    float inv = rsqrtf(var + 1e-5f);
    float2 g = *(const float2*)(gamma + tid * 2);
    float2 be = *(const float2*)(beta + tid * 2);
    float y0 = (v.x - mu) * inv * g.x + be.x;
    float y1 = (v.y - mu) * inv * g.y + be.y;
    float sy = y0 * y0 + y1 * y1;
    float am = fmaxf(fabsf(y0), fabsf(y1));
#pragma unroll
    for (int o = 32; o; o >>= 1) { sy += __shfl_xor(sy, o); am = fmaxf(am, __shfl_xor(am, o)); }
    __syncthreads();
    if (!lane) { r1[wv] = sy; r2[wv] = am; }
    __syncthreads();
    float sytot = r1[0] + r1[1] + r1[2] + r1[3];
    float amax = fmaxf(fmaxf(r2[0], r2[1]), fmaxf(r2[2], r2[3]));
    float rms = rsqrtf(sytot * (1.0f / KVE) + 1e-6f);
    float cl = fmaxf(amax * rms, 1e-5f);
    float kf = rms * (127.0f / cl);
    int q0 = max(-128, min(127, (int)rintf(y0 * kf)));
    int q1 = max(-128, min(127, (int)rintf(y1 * kf)));
    xq[(size_t)row * KVE + tid * 2]     = f2bf((float)q0);
    xq[(size_t)row * KVE + tid * 2 + 1] = f2bf((float)q1);
    if (!tid) dqv[row] = cl * (1.0f / 127.0f);
}

// ---------------------------------------------------------------------------
extern "C" void kernel_launch(void* const* d_in, const int* in_sizes, int n_in,
                              void* d_out, int out_size, void* d_ws, size_t ws_size,
                              hipStream_t stream)
{
    const float* query = (const float*)d_in[0];
    const float* key   = (const float*)d_in[1];
    const float* value = (const float*)d_in[2];
    const float* q_w   = (const float*)d_in[3];
    const float* k_w   = (const float*)d_in[4];
    const float* v_w   = (const float*)d_in[5];
    const float* out_w = (const float*)d_in[6];
    const float* ln_g  = (const float*)d_in[7];
    const float* ln_b  = (const float*)d_in[8];
    float* out = (float*)d_out;

    // workspace carve (all sizes multiples of 256B)
    char* p = (char*)d_ws;
    float* stats = (float*)p;  p += 256;
    short* wq_q = (short*)p;   p += (size_t)1024 * 1024 * 2;
    short* wq_k = (short*)p;   p += (size_t)512 * 1024 * 2;
    short* wq_v = (short*)p;   p += (size_t)512 * 1024 * 2;
    short* wq_o = (short*)p;   p += (size_t)1024 * 512 * 2;
    short* xq   = (short*)p;   p += (size_t)ROWS * 1024 * 2;
    float* dqv  = (float*)p;   p += (size_t)ROWS * 4;
    short* qb   = (short*)p;   p += (size_t)ROWS * E * 2;
    short* kb   = (short*)p;   p += (size_t)ROWS * KVE * 2;
    short* vb   = (short*)p;   p += (size_t)ROWS * KVE * 2;
    float* xb   = (float*)p;   p += (size_t)ROWS * KVE * 4;
    if ((size_t)(p - (char*)d_ws) > ws_size) return;

    dim3 blk(256);
    hipMemsetAsync(stats, 0, 256, stream);
    wstats_kernel<<<dim3(32, 4), blk, 0, stream>>>(q_w, k_w, v_w, out_w,
        1024 * 1024, 512 * 1024, 512 * 1024, 1024 * 512, stats);
    wquant_kernel<<<dim3(64, 4), blk, 0, stream>>>(q_w, k_w, v_w, out_w,
        1024 * 1024, 512 * 1024, 512 * 1024, 1024 * 512, stats, wq_q, wq_k, wq_v, wq_o);

    aquant_kernel<1024><<<ROWS, blk, 0, stream>>>(query, xq, dqv);
    gemm_bf16<false><<<dim3(8, 64), blk, 0, stream>>>(xq, wq_q, dqv, stats, 0,
        1.0f / (1024.0f * 1024.0f), qb, 1024, 1024);
    aquant_kernel<1024><<<ROWS, blk, 0, stream>>>(key, xq, dqv);
    gemm_bf16<false><<<dim3(4, 64), blk, 0, stream>>>(xq, wq_k, dqv, stats, 1,
        1.0f / (512.0f * 1024.0f), kb, 512, 1024);
    aquant_kernel<1024><<<ROWS, blk, 0, stream>>>(value, xq, dqv);
    gemm_bf16<false><<<dim3(4, 64), blk, 0, stream>>>(xq, wq_v, dqv, stats, 2,
        1.0f / (512.0f * 1024.0f), vb, 512, 1024);

    attn_mfma<<<dim3(SEQ / 64, H, B_), blk, 0, stream>>>(qb, kb, vb, xb);

    lnquant_kernel<<<ROWS, blk, 0, stream>>>(xb, ln_g, ln_b, xq, dqv);
    gemm_bf16<true><<<dim3(8, 64), blk, 0, stream>>>(xq, wq_o, dqv, stats, 3,
        1.0f / (1024.0f * 512.0f), out, 1024, 512);
}

// Round 3
// 384.813 us; speedup vs baseline: 5.0000x; 1.1328x over previous
//
#include <hip/hip_runtime.h>
#include <cstdint>
#include <cstddef>

// Problem constants
constexpr int B_   = 4;
constexpr int SEQ  = 2048;
constexpr int E    = 1024;   // embed dim
constexpr int KVE  = 512;    // kv embed dim
constexpr int H    = 4;      // kv heads
constexpr int ROWS = B_ * SEQ;   // 8192 tokens

typedef short short8  __attribute__((ext_vector_type(8)));
typedef short short4v __attribute__((ext_vector_type(4)));
typedef float floatx4 __attribute__((ext_vector_type(4)));

__device__ inline short f2bf(float f) {   // RNE float->bf16
    uint32_t u = __builtin_bit_cast(uint32_t, f);
    u = (u + 0x7fff + ((u >> 16) & 1)) >> 16;
    return (short)u;
}
__device__ inline float bf2f(short s) {
    return __builtin_bit_cast(float, (uint32_t)(uint16_t)s << 16);
}
__device__ inline void gl_lds16(const void* g, void* l) {
    __builtin_amdgcn_global_load_lds(
        (const __attribute__((address_space(1))) unsigned int*)g,
        (__attribute__((address_space(3))) unsigned int*)l, 16, 0, 0);
}

// ---------------------------------------------------------------------------
// Weight stats: per-matrix sum(w) and sum(|w|)
// ---------------------------------------------------------------------------
__global__ __launch_bounds__(256) void wstats_kernel(
    const float* __restrict__ w0, const float* __restrict__ w1,
    const float* __restrict__ w2, const float* __restrict__ w3,
    int n0, int n1, int n2, int n3, float* __restrict__ stats)
{
    int m = blockIdx.y;
    const float* w = (m == 0) ? w0 : (m == 1) ? w1 : (m == 2) ? w2 : w3;
    int n = (m == 0) ? n0 : (m == 1) ? n1 : (m == 2) ? n2 : n3;
    float s = 0.f, sa = 0.f;
    for (int i = blockIdx.x * 256 + threadIdx.x; i < n; i += gridDim.x * 256) {
        float x = w[i];
        s += x; sa += fabsf(x);
    }
#pragma unroll
    for (int o = 32; o; o >>= 1) { s += __shfl_xor(s, o); sa += __shfl_xor(sa, o); }
    __shared__ float ls[4], lsa[4];
    int lane = threadIdx.x & 63, wv = threadIdx.x >> 6;
    if (!lane) { ls[wv] = s; lsa[wv] = sa; }
    __syncthreads();
    if (!threadIdx.x) {
        atomicAdd(&stats[2 * m],     ls[0] + ls[1] + ls[2] + ls[3]);
        atomicAdd(&stats[2 * m + 1], lsa[0] + lsa[1] + lsa[2] + lsa[3]);
    }
}

// ---------------------------------------------------------------------------
// Weight ternary quant -> bf16 {-1,0,+1}
// ---------------------------------------------------------------------------
__global__ __launch_bounds__(256) void wquant_kernel(
    const float* __restrict__ w0, const float* __restrict__ w1,
    const float* __restrict__ w2, const float* __restrict__ w3,
    int n0, int n1, int n2, int n3, const float* __restrict__ stats,
    short* __restrict__ o0, short* __restrict__ o1,
    short* __restrict__ o2, short* __restrict__ o3)
{
    int m = blockIdx.y;
    const float* w = (m == 0) ? w0 : (m == 1) ? w1 : (m == 2) ? w2 : w3;
    int n = (m == 0) ? n0 : (m == 1) ? n1 : (m == 2) ? n2 : n3;
    short* o = (m == 0) ? o0 : (m == 1) ? o1 : (m == 2) ? o2 : o3;
    float e = stats[2 * m] / (float)n;
    int n4 = n >> 2;
    for (int i = blockIdx.x * 256 + threadIdx.x; i < n4; i += gridDim.x * 256) {
        float4 x = ((const float4*)w)[i];
        short4v q;
        q.x = (x.x > e) ? (short)0x3F80 : (x.x < e) ? (short)0xBF80 : (short)0;
        q.y = (x.y > e) ? (short)0x3F80 : (x.y < e) ? (short)0xBF80 : (short)0;
        q.z = (x.z > e) ? (short)0x3F80 : (x.z < e) ? (short)0xBF80 : (short)0;
        q.w = (x.w > e) ? (short)0x3F80 : (x.w < e) ? (short)0xBF80 : (short)0;
        *(short4v*)(o + ((size_t)i << 2)) = q;
    }
}

// ---------------------------------------------------------------------------
// Activation quant (fused q/k/v): RMSNorm -> int8 stored as exact bf16
// grid (ROWS, 3); z selects input tensor and output slice.
// ---------------------------------------------------------------------------
__global__ __launch_bounds__(256) void aquant3_kernel(
    const float* __restrict__ q, const float* __restrict__ k,
    const float* __restrict__ vv, short* __restrict__ xq01,
    short* __restrict__ xq2, float* __restrict__ dqv)
{
    int z = blockIdx.y;
    const float* x = (z == 0) ? q : (z == 1) ? k : vv;
    short* xq = (z == 2) ? xq2 : xq01 + (size_t)z * ROWS * E;
    float* dq = dqv + (size_t)z * ROWS;
    int tid = threadIdx.x;
    size_t base = (size_t)blockIdx.x * E;
    float4 t = *(const float4*)(x + base + tid * 4);
    float v[4] = { t.x, t.y, t.z, t.w };
    float ss = 0.f, am = 0.f;
#pragma unroll
    for (int i = 0; i < 4; i++) { ss += v[i] * v[i]; am = fmaxf(am, fabsf(v[i])); }
#pragma unroll
    for (int o = 32; o; o >>= 1) { ss += __shfl_xor(ss, o); am = fmaxf(am, __shfl_xor(am, o)); }
    __shared__ float l1[4], l2[4];
    int lane = tid & 63, wv = tid >> 6;
    if (!lane) { l1[wv] = ss; l2[wv] = am; }
    __syncthreads();
    ss = l1[0] + l1[1] + l1[2] + l1[3];
    am = fmaxf(fmaxf(l2[0], l2[1]), fmaxf(l2[2], l2[3]));
    float rms = rsqrtf(ss * (1.0f / E) + 1e-6f);
    float cl  = fmaxf(am * rms, 1e-5f);
    float kf  = rms * (127.0f / cl);
    short4v pk;
#pragma unroll
    for (int i = 0; i < 4; i++) {
        int qi = (int)rintf(v[i] * kf);
        qi = max(-128, min(127, qi));
        pk[i] = f2bf((float)qi);
    }
    *(short4v*)(xq + base + tid * 4) = pk;
    if (!tid) dq[blockIdx.x] = cl * (1.0f / 127.0f);
}

// ---------------------------------------------------------------------------
// bf16 MFMA GEMM body (bit-exact). 128x128 tile, BK=32, global_load_lds w16.
// ---------------------------------------------------------------------------
template <bool F32OUT>
__device__ inline void gemm_body(
    const short* __restrict__ A, const short* __restrict__ W,
    const float* __restrict__ dqv, float sw, void* __restrict__ Cout,
    int O, int K, short* As, short* Ws, size_t row0, size_t c0)
{
    int tid = threadIdx.x;
    int w = tid >> 6, lane = tid & 63;
    int quad = lane >> 4, l15 = lane & 15;
    int mbase = (w & 1) * 64, nbase = (w >> 1) * 64;

    floatx4 acc[4][4];
#pragma unroll
    for (int i = 0; i < 4; i++)
#pragma unroll
        for (int j = 0; j < 4; j++) acc[i][j] = (floatx4){0.f, 0.f, 0.f, 0.f};

    int cA0 = tid, cA1 = tid + 256;
    int rA0 = cA0 >> 2, gA0 = (cA0 & 3) ^ (rA0 & 3);
    int rA1 = cA1 >> 2, gA1 = (cA1 & 3) ^ (rA1 & 3);
    const short* Ag0 = A + (row0 + rA0) * K + gA0 * 8;
    const short* Ag1 = A + (row0 + rA1) * K + gA1 * 8;
    const short* Wg0 = W + (c0 + rA0) * K + gA0 * 8;
    const short* Wg1 = W + (c0 + rA1) * K + gA1 * 8;
    short* lA0 = As + cA0 * 8;  short* lA1 = As + cA1 * 8;
    short* lW0 = Ws + cA0 * 8;  short* lW1 = Ws + cA1 * 8;

    for (int kt = 0; kt < K; kt += 32) {
        __syncthreads();
        gl_lds16(Ag0 + kt, lA0);
        gl_lds16(Ag1 + kt, lA1);
        gl_lds16(Wg0 + kt, lW0);
        gl_lds16(Wg1 + kt, lW1);
        __syncthreads();
        short8 af[4], bfr[4];
#pragma unroll
        for (int mt = 0; mt < 4; mt++) {
            int row = mbase + mt * 16 + l15;
            int pos = quad ^ (row & 3);
            af[mt] = *(const short8*)(As + row * 32 + pos * 8);
        }
#pragma unroll
        for (int nt = 0; nt < 4; nt++) {
            int row = nbase + nt * 16 + l15;
            int pos = quad ^ (row & 3);
            bfr[nt] = *(const short8*)(Ws + row * 32 + pos * 8);
        }
#pragma unroll
        for (int mt = 0; mt < 4; mt++)
#pragma unroll
            for (int nt = 0; nt < 4; nt++)
                acc[mt][nt] = __builtin_amdgcn_mfma_f32_16x16x32_bf16(
                    af[mt], bfr[nt], acc[mt][nt], 0, 0, 0);
    }

#pragma unroll
    for (int mt = 0; mt < 4; mt++) {
#pragma unroll
        for (int r = 0; r < 4; r++) {
            size_t grow = row0 + mbase + mt * 16 + quad * 4 + r;
            float scv = sw * dqv[grow];
#pragma unroll
            for (int nt = 0; nt < 4; nt++) {
                size_t gcol = c0 + nbase + nt * 16 + l15;
                float v = acc[mt][nt][r] * scv;
                if constexpr (F32OUT) ((float*)Cout)[grow * O + gcol] = v;
                else                  ((short*)Cout)[grow * O + gcol] = f2bf(v);
            }
        }
    }
}

// Batched QKV GEMM: grid (8, 64, 3); z>0 uses only x<4.
__global__ __launch_bounds__(256) void gemm_qkv(
    const short* __restrict__ xq01, const short* __restrict__ xq2,
    const short* __restrict__ wq_q, const short* __restrict__ wq_k,
    const short* __restrict__ wq_v, const float* __restrict__ dqv,
    const float* __restrict__ stats,
    short* __restrict__ qb, short* __restrict__ kb, short* __restrict__ vb)
{
    __shared__ short As[128 * 32];
    __shared__ short Ws[128 * 32];
    int z = blockIdx.z;
    if (z && blockIdx.x >= 4) return;
    int O = z ? KVE : E;
    const short* A = (z == 0) ? xq01 : (z == 1) ? xq01 + (size_t)ROWS * E : xq2;
    const short* W = (z == 0) ? wq_q : (z == 1) ? wq_k : wq_v;
    short* outp = (z == 0) ? qb : (z == 1) ? kb : vb;
    float sw = stats[2 * z + 1] / (float)(O * E);
    gemm_body<false>(A, W, dqv + (size_t)z * ROWS, sw, outp, O, E, As, Ws,
                     (size_t)blockIdx.y * 128, (size_t)blockIdx.x * 128);
}

// Output GEMM (fp32 out, K=512)
__global__ __launch_bounds__(256) void gemm_out(
    const short* __restrict__ A, const short* __restrict__ W,
    const float* __restrict__ dqv, const float* __restrict__ stats,
    float* __restrict__ Cout)
{
    __shared__ short As[128 * 32];
    __shared__ short Ws[128 * 32];
    float sw = stats[7] / (float)(E * KVE);
    gemm_body<true>(A, W, dqv, sw, Cout, E, KVE, As, Ws,
                    (size_t)blockIdx.y * 128, (size_t)blockIdx.x * 128);
}

// ---------------------------------------------------------------------------
// MFMA flash attention v2: reg-prefetch pipeline, Q staged via Ks, 3 blk/CU.
// Block: 64 q-rows x (kv-head h, batch b). 4 waves, wave owns 16 q-rows.
// Pads: Ks stride 140 (70 dw = 6 mod 32), Vt/Ps stride 76 (38 dw = 6 mod 32).
// ---------------------------------------------------------------------------
__global__ __launch_bounds__(256, 3) void attn_mfma(
    const short* __restrict__ qb, const short* __restrict__ kb,
    const short* __restrict__ vb, float* __restrict__ xb)
{
    __shared__ short Ks[64][140];
    __shared__ short Vt[128][76];
    __shared__ short Ps[64][76];
    int tid = threadIdx.x;
    int w = tid >> 6, lane = tid & 63, quad = lane >> 4, l15 = lane & 15;
    int blk = blockIdx.x, h = blockIdx.y, b = blockIdx.z;
    size_t qrow0 = (size_t)(b * SEQ + blk * 64);

    int sK = tid >> 2, cK = tid & 3;          // K/Q staging: row, 32-col chunk
    int sV = (tid & 15) * 4, dV = tid >> 4;   // V staging: 4 rows, 8-col chunk

    // ---- prefetch KV tile 0 into registers (latency hidden by Q staging)
    short8 kreg[4], vreg[4];
    {
        size_t srow0 = (size_t)(b * SEQ);
        const short* ksrc = kb + (srow0 + sK) * KVE + h * 128 + cK * 32;
#pragma unroll
        for (int j = 0; j < 4; j++) kreg[j] = *(const short8*)(ksrc + j * 8);
        const short* vsrc = vb + (srow0 + sV) * KVE + h * 128 + dV * 8;
#pragma unroll
        for (int j = 0; j < 4; j++) vreg[j] = *(const short8*)(vsrc + j * KVE);
    }

    // ---- stage Q via Ks: sum grouped head pair, fold 1/(scale^2) = 1/128
    {
        const short* src = qb + (qrow0 + sK) * E + h * 256 + cK * 32;
#pragma unroll
        for (int j = 0; j < 4; j++) {
            short8 a  = *(const short8*)(src + j * 8);
            short8 b2 = *(const short8*)(src + 128 + j * 8);
            short8 o;
#pragma unroll
            for (int e = 0; e < 8; e++)
                o[e] = f2bf((bf2f(a[e]) + bf2f(b2[e])) * (1.0f / 128.0f));
            *(short8*)&Ks[sK][cK * 32 + j * 8] = o;
        }
    }
    __syncthreads();
    short8 qa[4];
#pragma unroll
    for (int ks = 0; ks < 4; ks++)
        qa[ks] = *(const short8*)&Ks[w * 16 + l15][ks * 32 + quad * 8];

    floatx4 oacc[8];
#pragma unroll
    for (int i = 0; i < 8; i++) oacc[i] = (floatx4){0.f, 0.f, 0.f, 0.f};
    float m_r[4] = {-1e30f, -1e30f, -1e30f, -1e30f};
    float l_r[4] = {0.f, 0.f, 0.f, 0.f};

    for (int st = 0; st < SEQ / 64; st++) {
        __syncthreads();   // prior readers of Ks/Vt done (incl. qa extraction)
        // commit prefetched K tile
#pragma unroll
        for (int j = 0; j < 4; j++)
            *(short8*)&Ks[sK][cK * 32 + j * 8] = kreg[j];
        // commit prefetched V tile (transposed)
#pragma unroll
        for (int i = 0; i < 8; i++) {
            short4v vv = { vreg[0][i], vreg[1][i], vreg[2][i], vreg[3][i] };
            *(short4v*)&Vt[dV * 8 + i][sV] = vv;
        }
        // issue next tile's global loads (hidden behind this tile's compute)
        if (st + 1 < SEQ / 64) {
            size_t srow0 = (size_t)(b * SEQ + (st + 1) * 64);
            const short* ksrc = kb + (srow0 + sK) * KVE + h * 128 + cK * 32;
#pragma unroll
            for (int j = 0; j < 4; j++) kreg[j] = *(const short8*)(ksrc + j * 8);
            const short* vsrc = vb + (srow0 + sV) * KVE + h * 128 + dV * 8;
#pragma unroll
            for (int j = 0; j < 4; j++) vreg[j] = *(const short8*)(vsrc + j * KVE);
        }
        __syncthreads();
        // QK^T: wave's 16 q-rows x 64 s-cols
        floatx4 sc[4];
#pragma unroll
        for (int nt = 0; nt < 4; nt++) {
            floatx4 a = (floatx4){0.f, 0.f, 0.f, 0.f};
#pragma unroll
            for (int ks = 0; ks < 4; ks++) {
                short8 kf = *(const short8*)&Ks[nt * 16 + l15][ks * 32 + quad * 8];
                a = __builtin_amdgcn_mfma_f32_16x16x32_bf16(qa[ks], kf, a, 0, 0, 0);
            }
            sc[nt] = a;
        }
        // online softmax: row = quad*4 + r, cols spread over 16-lane groups
        float alpha[4];
#pragma unroll
        for (int r = 0; r < 4; r++) {
            float mx = fmaxf(fmaxf(sc[0][r], sc[1][r]), fmaxf(sc[2][r], sc[3][r]));
#pragma unroll
            for (int o = 1; o < 16; o <<= 1) mx = fmaxf(mx, __shfl_xor(mx, o));
            float nm = fmaxf(m_r[r], mx);
            alpha[r] = __expf(m_r[r] - nm);
            m_r[r] = nm;
            float rs = 0.f;
#pragma unroll
            for (int nt = 0; nt < 4; nt++) {
                float p = __expf(sc[nt][r] - nm);
                sc[nt][r] = p;
                rs += p;
            }
#pragma unroll
            for (int o = 1; o < 16; o <<= 1) rs += __shfl_xor(rs, o);
            l_r[r] = l_r[r] * alpha[r] + rs;
        }
        // P -> LDS (own wave's rows only; no barrier needed)
#pragma unroll
        for (int nt = 0; nt < 4; nt++)
#pragma unroll
            for (int r = 0; r < 4; r++)
                Ps[w * 16 + quad * 4 + r][nt * 16 + l15] = f2bf(sc[nt][r]);
        // rescale O
#pragma unroll
        for (int nt = 0; nt < 8; nt++)
#pragma unroll
            for (int r = 0; r < 4; r++) oacc[nt][r] *= alpha[r];
        // PV
        short8 pa0 = *(const short8*)&Ps[w * 16 + l15][quad * 8];
        short8 pa1 = *(const short8*)&Ps[w * 16 + l15][32 + quad * 8];
#pragma unroll
        for (int nt = 0; nt < 8; nt++) {
            short8 vf0 = *(const short8*)&Vt[nt * 16 + l15][quad * 8];
            short8 vf1 = *(const short8*)&Vt[nt * 16 + l15][32 + quad * 8];
            oacc[nt] = __builtin_amdgcn_mfma_f32_16x16x32_bf16(pa0, vf0, oacc[nt], 0, 0, 0);
            oacc[nt] = __builtin_amdgcn_mfma_f32_16x16x32_bf16(pa1, vf1, oacc[nt], 0, 0, 0);
        }
    }
#pragma unroll
    for (int r = 0; r < 4; r++) {
        float inv = 1.0f / l_r[r];
        size_t grow = qrow0 + w * 16 + quad * 4 + r;
        float* dst = xb + grow * KVE + h * 128;
#pragma unroll
        for (int nt = 0; nt < 8; nt++)
            dst[nt * 16 + l15] = oacc[nt][r] * inv;
    }
}

// ---------------------------------------------------------------------------
// LayerNorm + RMSNorm + int8 quant (stored as exact bf16), one block per row
// ---------------------------------------------------------------------------
__global__ __launch_bounds__(256) void lnquant_kernel(
    const float* __restrict__ x, const float* __restrict__ gamma,
    const float* __restrict__ beta, short* __restrict__ xq, float* __restrict__ dqv)
{
    int row = blockIdx.x, tid = threadIdx.x;
    float2 v = *(const float2*)(x + (size_t)row * KVE + tid * 2);
    float s = v.x + v.y, ss = v.x * v.x + v.y * v.y;
#pragma unroll
    for (int o = 32; o; o >>= 1) { s += __shfl_xor(s, o); ss += __shfl_xor(ss, o); }
    __shared__ float r1[4], r2[4];
    int lane = tid & 63, wv = tid >> 6;
    if (!lane) { r1[wv] = s; r2[wv] = ss; }
    __syncthreads();
    float stot = r1[0] + r1[1] + r1[2] + r1[3];
    float sstot = r2[0] + r2[1] + r2[2] + r2[3];
    float mu = stot * (1.0f / KVE);
    float var = fmaxf(sstot * (1.0f / KVE) - mu * mu, 0.0f);
    float inv = rsqrtf(var + 1e-5f);
    float2 g = *(const float2*)(gamma + tid * 2);
    float2 be = *(const float2*)(beta + tid * 2);
    float y0 = (v.x - mu) * inv * g.x + be.x;
    float y1 = (v.y - mu) * inv * g.y + be.y;
    float sy = y0 * y0 + y1 * y1;
    float am = fmaxf(fabsf(y0), fabsf(y1));
#pragma unroll
    for (int o = 32; o; o >>= 1) { sy += __shfl_xor(sy, o); am = fmaxf(am, __shfl_xor(am, o)); }
    __syncthreads();
    if (!lane) { r1[wv] = sy; r2[wv] = am; }
    __syncthreads();
    float sytot = r1[0] + r1[1] + r1[2] + r1[3];
    float amax = fmaxf(fmaxf(r2[0], r2[1]), fmaxf(r2[2], r2[3]));
    float rms = rsqrtf(sytot * (1.0f / KVE) + 1e-6f);
    float cl = fmaxf(amax * rms, 1e-5f);
    float kf = rms * (127.0f / cl);
    int q0 = max(-128, min(127, (int)rintf(y0 * kf)));
    int q1 = max(-128, min(127, (int)rintf(y1 * kf)));
    xq[(size_t)row * KVE + tid * 2]     = f2bf((float)q0);
    xq[(size_t)row * KVE + tid * 2 + 1] = f2bf((float)q1);
    if (!tid) dqv[row] = cl * (1.0f / 127.0f);
}

// ---------------------------------------------------------------------------
extern "C" void kernel_launch(void* const* d_in, const int* in_sizes, int n_in,
                              void* d_out, int out_size, void* d_ws, size_t ws_size,
                              hipStream_t stream)
{
    const float* query = (const float*)d_in[0];
    const float* key   = (const float*)d_in[1];
    const float* value = (const float*)d_in[2];
    const float* q_w   = (const float*)d_in[3];
    const float* k_w   = (const float*)d_in[4];
    const float* v_w   = (const float*)d_in[5];
    const float* out_w = (const float*)d_in[6];
    const float* ln_g  = (const float*)d_in[7];
    const float* ln_b  = (const float*)d_in[8];
    float* out = (float*)d_out;

    // workspace carve (xq slice 2 aliases xb: xq2 dead before attn writes xb)
    char* p = (char*)d_ws;
    float* stats = (float*)p;  p += 256;
    short* wq_q = (short*)p;   p += (size_t)1024 * 1024 * 2;
    short* wq_k = (short*)p;   p += (size_t)512 * 1024 * 2;
    short* wq_v = (short*)p;   p += (size_t)512 * 1024 * 2;
    short* wq_o = (short*)p;   p += (size_t)1024 * 512 * 2;
    short* xq01 = (short*)p;   p += (size_t)2 * ROWS * E * 2;
    float* dqv  = (float*)p;   p += (size_t)3 * ROWS * 4;
    short* qb   = (short*)p;   p += (size_t)ROWS * E * 2;
    short* kb   = (short*)p;   p += (size_t)ROWS * KVE * 2;
    short* vb   = (short*)p;   p += (size_t)ROWS * KVE * 2;
    float* xb   = (float*)p;   p += (size_t)ROWS * KVE * 4;
    short* xq2  = (short*)xb;  // alias: 16 MB, dead before attn runs
    if ((size_t)(p - (char*)d_ws) > ws_size) return;

    dim3 blk(256);
    hipMemsetAsync(stats, 0, 256, stream);
    wstats_kernel<<<dim3(64, 4), blk, 0, stream>>>(q_w, k_w, v_w, out_w,
        1024 * 1024, 512 * 1024, 512 * 1024, 1024 * 512, stats);
    wquant_kernel<<<dim3(64, 4), blk, 0, stream>>>(q_w, k_w, v_w, out_w,
        1024 * 1024, 512 * 1024, 512 * 1024, 1024 * 512, stats, wq_q, wq_k, wq_v, wq_o);

    aquant3_kernel<<<dim3(ROWS, 3), blk, 0, stream>>>(query, key, value, xq01, xq2, dqv);
    gemm_qkv<<<dim3(8, 64, 3), blk, 0, stream>>>(xq01, xq2, wq_q, wq_k, wq_v,
        dqv, stats, qb, kb, vb);

    attn_mfma<<<dim3(SEQ / 64, H, B_), blk, 0, stream>>>(qb, kb, vb, xb);

    lnquant_kernel<<<ROWS, blk, 0, stream>>>(xb, ln_g, ln_b, xq01, dqv);
    gemm_out<<<dim3(8, 64), blk, 0, stream>>>(xq01, wq_o, dqv, stats, out);
}

// Round 4
// 368.492 us; speedup vs baseline: 5.2215x; 1.0443x over previous
//
#include <hip/hip_runtime.h>
#include <cstdint>
#include <cstddef>

// Problem constants
constexpr int B_   = 4;
constexpr int SEQ  = 2048;
constexpr int E    = 1024;   // embed dim
constexpr int KVE  = 512;    // kv embed dim
constexpr int H    = 4;      // kv heads
constexpr int ROWS = B_ * SEQ;   // 8192 tokens

typedef short short8  __attribute__((ext_vector_type(8)));
typedef short short4v __attribute__((ext_vector_type(4)));
typedef float floatx4 __attribute__((ext_vector_type(4)));

__device__ inline short f2bf(float f) {   // RNE float->bf16
    uint32_t u = __builtin_bit_cast(uint32_t, f);
    u = (u + 0x7fff + ((u >> 16) & 1)) >> 16;
    return (short)u;
}
__device__ inline float bf2f(short s) {
    return __builtin_bit_cast(float, (uint32_t)(uint16_t)s << 16);
}
__device__ inline void gl_lds16(const void* g, void* l) {
    __builtin_amdgcn_global_load_lds(
        (const __attribute__((address_space(1))) unsigned int*)g,
        (__attribute__((address_space(3))) unsigned int*)l, 16, 0, 0);
}

// ---------------------------------------------------------------------------
// Weight stats: per-matrix sum(w) and sum(|w|)
// ---------------------------------------------------------------------------
__global__ __launch_bounds__(256) void wstats_kernel(
    const float* __restrict__ w0, const float* __restrict__ w1,
    const float* __restrict__ w2, const float* __restrict__ w3,
    int n0, int n1, int n2, int n3, float* __restrict__ stats)
{
    int m = blockIdx.y;
    const float* w = (m == 0) ? w0 : (m == 1) ? w1 : (m == 2) ? w2 : w3;
    int n = (m == 0) ? n0 : (m == 1) ? n1 : (m == 2) ? n2 : n3;
    float s = 0.f, sa = 0.f;
    for (int i = blockIdx.x * 256 + threadIdx.x; i < n; i += gridDim.x * 256) {
        float x = w[i];
        s += x; sa += fabsf(x);
    }
#pragma unroll
    for (int o = 32; o; o >>= 1) { s += __shfl_xor(s, o); sa += __shfl_xor(sa, o); }
    __shared__ float ls[4], lsa[4];
    int lane = threadIdx.x & 63, wv = threadIdx.x >> 6;
    if (!lane) { ls[wv] = s; lsa[wv] = sa; }
    __syncthreads();
    if (!threadIdx.x) {
        atomicAdd(&stats[2 * m],     ls[0] + ls[1] + ls[2] + ls[3]);
        atomicAdd(&stats[2 * m + 1], lsa[0] + lsa[1] + lsa[2] + lsa[3]);
    }
}

// ---------------------------------------------------------------------------
// Weight ternary quant -> bf16 {-1,0,+1}
// ---------------------------------------------------------------------------
__global__ __launch_bounds__(256) void wquant_kernel(
    const float* __restrict__ w0, const float* __restrict__ w1,
    const float* __restrict__ w2, const float* __restrict__ w3,
    int n0, int n1, int n2, int n3, const float* __restrict__ stats,
    short* __restrict__ o0, short* __restrict__ o1,
    short* __restrict__ o2, short* __restrict__ o3)
{
    int m = blockIdx.y;
    const float* w = (m == 0) ? w0 : (m == 1) ? w1 : (m == 2) ? w2 : w3;
    int n = (m == 0) ? n0 : (m == 1) ? n1 : (m == 2) ? n2 : n3;
    short* o = (m == 0) ? o0 : (m == 1) ? o1 : (m == 2) ? o2 : o3;
    float e = stats[2 * m] / (float)n;
    int n4 = n >> 2;
    for (int i = blockIdx.x * 256 + threadIdx.x; i < n4; i += gridDim.x * 256) {
        float4 x = ((const float4*)w)[i];
        short4v q;
        q.x = (x.x > e) ? (short)0x3F80 : (x.x < e) ? (short)0xBF80 : (short)0;
        q.y = (x.y > e) ? (short)0x3F80 : (x.y < e) ? (short)0xBF80 : (short)0;
        q.z = (x.z > e) ? (short)0x3F80 : (x.z < e) ? (short)0xBF80 : (short)0;
        q.w = (x.w > e) ? (short)0x3F80 : (x.w < e) ? (short)0xBF80 : (short)0;
        *(short4v*)(o + ((size_t)i << 2)) = q;
    }
}

// ---------------------------------------------------------------------------
// Activation quant (fused q/k/v): RMSNorm -> int8 stored as exact bf16
// ---------------------------------------------------------------------------
__global__ __launch_bounds__(256) void aquant3_kernel(
    const float* __restrict__ q, const float* __restrict__ k,
    const float* __restrict__ vv, short* __restrict__ xq01,
    short* __restrict__ xq2, float* __restrict__ dqv)
{
    int z = blockIdx.y;
    const float* x = (z == 0) ? q : (z == 1) ? k : vv;
    short* xq = (z == 2) ? xq2 : xq01 + (size_t)z * ROWS * E;
    float* dq = dqv + (size_t)z * ROWS;
    int tid = threadIdx.x;
    size_t base = (size_t)blockIdx.x * E;
    float4 t = *(const float4*)(x + base + tid * 4);
    float v[4] = { t.x, t.y, t.z, t.w };
    float ss = 0.f, am = 0.f;
#pragma unroll
    for (int i = 0; i < 4; i++) { ss += v[i] * v[i]; am = fmaxf(am, fabsf(v[i])); }
#pragma unroll
    for (int o = 32; o; o >>= 1) { ss += __shfl_xor(ss, o); am = fmaxf(am, __shfl_xor(am, o)); }
    __shared__ float l1[4], l2[4];
    int lane = tid & 63, wv = tid >> 6;
    if (!lane) { l1[wv] = ss; l2[wv] = am; }
    __syncthreads();
    ss = l1[0] + l1[1] + l1[2] + l1[3];
    am = fmaxf(fmaxf(l2[0], l2[1]), fmaxf(l2[2], l2[3]));
    float rms = rsqrtf(ss * (1.0f / E) + 1e-6f);
    float cl  = fmaxf(am * rms, 1e-5f);
    float kf  = rms * (127.0f / cl);
    short4v pk;
#pragma unroll
    for (int i = 0; i < 4; i++) {
        int qi = (int)rintf(v[i] * kf);
        qi = max(-128, min(127, qi));
        pk[i] = f2bf((float)qi);
    }
    *(short4v*)(xq + base + tid * 4) = pk;
    if (!tid) dq[blockIdx.x] = cl * (1.0f / 127.0f);
}

// ---------------------------------------------------------------------------
// bf16 MFMA GEMM body (bit-exact). 128x128 tile, BK=32, global_load_lds w16.
// ---------------------------------------------------------------------------
template <bool F32OUT>
__device__ inline void gemm_body(
    const short* __restrict__ A, const short* __restrict__ W,
    const float* __restrict__ dqv, float sw, void* __restrict__ Cout,
    int O, int K, short* As, short* Ws, size_t row0, size_t c0)
{
    int tid = threadIdx.x;
    int w = tid >> 6, lane = tid & 63;
    int quad = lane >> 4, l15 = lane & 15;
    int mbase = (w & 1) * 64, nbase = (w >> 1) * 64;

    floatx4 acc[4][4];
#pragma unroll
    for (int i = 0; i < 4; i++)
#pragma unroll
        for (int j = 0; j < 4; j++) acc[i][j] = (floatx4){0.f, 0.f, 0.f, 0.f};

    int cA0 = tid, cA1 = tid + 256;
    int rA0 = cA0 >> 2, gA0 = (cA0 & 3) ^ (rA0 & 3);
    int rA1 = cA1 >> 2, gA1 = (cA1 & 3) ^ (rA1 & 3);
    const short* Ag0 = A + (row0 + rA0) * K + gA0 * 8;
    const short* Ag1 = A + (row0 + rA1) * K + gA1 * 8;
    const short* Wg0 = W + (c0 + rA0) * K + gA0 * 8;
    const short* Wg1 = W + (c0 + rA1) * K + gA1 * 8;
    short* lA0 = As + cA0 * 8;  short* lA1 = As + cA1 * 8;
    short* lW0 = Ws + cA0 * 8;  short* lW1 = Ws + cA1 * 8;

    for (int kt = 0; kt < K; kt += 32) {
        __syncthreads();
        gl_lds16(Ag0 + kt, lA0);
        gl_lds16(Ag1 + kt, lA1);
        gl_lds16(Wg0 + kt, lW0);
        gl_lds16(Wg1 + kt, lW1);
        __syncthreads();
        short8 af[4], bfr[4];
#pragma unroll
        for (int mt = 0; mt < 4; mt++) {
            int row = mbase + mt * 16 + l15;
            int pos = quad ^ (row & 3);
            af[mt] = *(const short8*)(As + row * 32 + pos * 8);
        }
#pragma unroll
        for (int nt = 0; nt < 4; nt++) {
            int row = nbase + nt * 16 + l15;
            int pos = quad ^ (row & 3);
            bfr[nt] = *(const short8*)(Ws + row * 32 + pos * 8);
        }
#pragma unroll
        for (int mt = 0; mt < 4; mt++)
#pragma unroll
            for (int nt = 0; nt < 4; nt++)
                acc[mt][nt] = __builtin_amdgcn_mfma_f32_16x16x32_bf16(
                    af[mt], bfr[nt], acc[mt][nt], 0, 0, 0);
    }

#pragma unroll
    for (int mt = 0; mt < 4; mt++) {
#pragma unroll
        for (int r = 0; r < 4; r++) {
            size_t grow = row0 + mbase + mt * 16 + quad * 4 + r;
            float scv = sw * dqv[grow];
#pragma unroll
            for (int nt = 0; nt < 4; nt++) {
                size_t gcol = c0 + nbase + nt * 16 + l15;
                float v = acc[mt][nt][r] * scv;
                if constexpr (F32OUT) ((float*)Cout)[grow * O + gcol] = v;
                else                  ((short*)Cout)[grow * O + gcol] = f2bf(v);
            }
        }
    }
}

// Batched QKV GEMM: flat 1024-block grid (512 q / 256 k / 256 v tiles).
__global__ __launch_bounds__(256) void gemm_qkv(
    const short* __restrict__ xq01, const short* __restrict__ xq2,
    const short* __restrict__ wq_q, const short* __restrict__ wq_k,
    const short* __restrict__ wq_v, const float* __restrict__ dqv,
    const float* __restrict__ stats,
    short* __restrict__ qb, short* __restrict__ kb, short* __restrict__ vb)
{
    __shared__ short As[128 * 32];
    __shared__ short Ws[128 * 32];
    int id = blockIdx.x;
    int z, bx, by;
    if (id < 512)      { z = 0; bx = id & 7; by = id >> 3; }
    else if (id < 768) { z = 1; int t = id - 512; bx = t & 3; by = t >> 2; }
    else               { z = 2; int t = id - 768; bx = t & 3; by = t >> 2; }
    int O = z ? KVE : E;
    const short* A = (z == 0) ? xq01 : (z == 1) ? xq01 + (size_t)ROWS * E : xq2;
    const short* W = (z == 0) ? wq_q : (z == 1) ? wq_k : wq_v;
    short* outp = (z == 0) ? qb : (z == 1) ? kb : vb;
    float sw = stats[2 * z + 1] / (float)(O * E);
    gemm_body<false>(A, W, dqv + (size_t)z * ROWS, sw, outp, O, E, As, Ws,
                     (size_t)by * 128, (size_t)bx * 128);
}

// Output GEMM (fp32 out, K=512)
__global__ __launch_bounds__(256) void gemm_out(
    const short* __restrict__ A, const short* __restrict__ W,
    const float* __restrict__ dqv, const float* __restrict__ stats,
    float* __restrict__ Cout)
{
    __shared__ short As[128 * 32];
    __shared__ short Ws[128 * 32];
    float sw = stats[7] / (float)(E * KVE);
    gemm_body<true>(A, W, dqv, sw, Cout, E, KVE, As, Ws,
                    (size_t)blockIdx.y * 128, (size_t)blockIdx.x * 128);
}

// ---------------------------------------------------------------------------
// MFMA flash attention v3: 2-way KV split (flash-decode), reg-prefetch,
// Q staged via Ks. Grid (SEQ/64, H, B*2); z = b*2 + half; 16 S-tiles/block.
// Emits normalized partial O + per-(row,head) (m, l) for the fused combine.
// ---------------------------------------------------------------------------
__global__ __launch_bounds__(256, 3) void attn_mfma(
    const short* __restrict__ qb, const short* __restrict__ kb,
    const short* __restrict__ vb, float* __restrict__ opart,
    float* __restrict__ mlbuf)
{
    __shared__ short Ks[64][140];
    __shared__ short Vt[128][76];
    __shared__ short Ps[64][76];
    int tid = threadIdx.x;
    int w = tid >> 6, lane = tid & 63, quad = lane >> 4, l15 = lane & 15;
    int blk = blockIdx.x, h = blockIdx.y;
    int b = blockIdx.z >> 1, half = blockIdx.z & 1;
    size_t qrow0 = (size_t)(b * SEQ + blk * 64);
    size_t sbase = (size_t)(b * SEQ + half * (SEQ / 2));

    int sK = tid >> 2, cK = tid & 3;          // K/Q staging: row, 32-col chunk
    int sV = (tid & 15) * 4, dV = tid >> 4;   // V staging: 4 rows, 8-col chunk

    // ---- prefetch KV tile 0 into registers (latency hidden by Q staging)
    short8 kreg[4], vreg[4];
    {
        const short* ksrc = kb + (sbase + sK) * KVE + h * 128 + cK * 32;
#pragma unroll
        for (int j = 0; j < 4; j++) kreg[j] = *(const short8*)(ksrc + j * 8);
        const short* vsrc = vb + (sbase + sV) * KVE + h * 128 + dV * 8;
#pragma unroll
        for (int j = 0; j < 4; j++) vreg[j] = *(const short8*)(vsrc + j * KVE);
    }

    // ---- stage Q via Ks: sum grouped head pair, fold 1/(scale^2) = 1/128
    {
        const short* src = qb + (qrow0 + sK) * E + h * 256 + cK * 32;
#pragma unroll
        for (int j = 0; j < 4; j++) {
            short8 a  = *(const short8*)(src + j * 8);
            short8 b2 = *(const short8*)(src + 128 + j * 8);
            short8 o;
#pragma unroll
            for (int e = 0; e < 8; e++)
                o[e] = f2bf((bf2f(a[e]) + bf2f(b2[e])) * (1.0f / 128.0f));
            *(short8*)&Ks[sK][cK * 32 + j * 8] = o;
        }
    }
    __syncthreads();
    short8 qa[4];
#pragma unroll
    for (int ks = 0; ks < 4; ks++)
        qa[ks] = *(const short8*)&Ks[w * 16 + l15][ks * 32 + quad * 8];

    floatx4 oacc[8];
#pragma unroll
    for (int i = 0; i < 8; i++) oacc[i] = (floatx4){0.f, 0.f, 0.f, 0.f};
    float m_r[4] = {-1e30f, -1e30f, -1e30f, -1e30f};
    float l_r[4] = {0.f, 0.f, 0.f, 0.f};

    for (int st = 0; st < SEQ / 128; st++) {
        __syncthreads();   // prior readers of Ks/Vt done (incl. qa extraction)
        // commit prefetched K tile
#pragma unroll
        for (int j = 0; j < 4; j++)
            *(short8*)&Ks[sK][cK * 32 + j * 8] = kreg[j];
        // commit prefetched V tile (transposed)
#pragma unroll
        for (int i = 0; i < 8; i++) {
            short4v vv = { vreg[0][i], vreg[1][i], vreg[2][i], vreg[3][i] };
            *(short4v*)&Vt[dV * 8 + i][sV] = vv;
        }
        // issue next tile's global loads (hidden behind this tile's compute)
        if (st + 1 < SEQ / 128) {
            size_t srow0 = sbase + (size_t)(st + 1) * 64;
            const short* ksrc = kb + (srow0 + sK) * KVE + h * 128 + cK * 32;
#pragma unroll
            for (int j = 0; j < 4; j++) kreg[j] = *(const short8*)(ksrc + j * 8);
            const short* vsrc = vb + (srow0 + sV) * KVE + h * 128 + dV * 8;
#pragma unroll
            for (int j = 0; j < 4; j++) vreg[j] = *(const short8*)(vsrc + j * KVE);
        }
        __syncthreads();
        // QK^T: wave's 16 q-rows x 64 s-cols
        floatx4 sc[4];
#pragma unroll
        for (int nt = 0; nt < 4; nt++) {
            floatx4 a = (floatx4){0.f, 0.f, 0.f, 0.f};
#pragma unroll
            for (int ks = 0; ks < 4; ks++) {
                short8 kf = *(const short8*)&Ks[nt * 16 + l15][ks * 32 + quad * 8];
                a = __builtin_amdgcn_mfma_f32_16x16x32_bf16(qa[ks], kf, a, 0, 0, 0);
            }
            sc[nt] = a;
        }
        // online softmax: row = quad*4 + r, cols spread over 16-lane groups
        float alpha[4];
#pragma unroll
        for (int r = 0; r < 4; r++) {
            float mx = fmaxf(fmaxf(sc[0][r], sc[1][r]), fmaxf(sc[2][r], sc[3][r]));
#pragma unroll
            for (int o = 1; o < 16; o <<= 1) mx = fmaxf(mx, __shfl_xor(mx, o));
            float nm = fmaxf(m_r[r], mx);
            alpha[r] = __expf(m_r[r] - nm);
            m_r[r] = nm;
            float rs = 0.f;
#pragma unroll
            for (int nt = 0; nt < 4; nt++) {
                float p = __expf(sc[nt][r] - nm);
                sc[nt][r] = p;
                rs += p;
            }
#pragma unroll
            for (int o = 1; o < 16; o <<= 1) rs += __shfl_xor(rs, o);
            l_r[r] = l_r[r] * alpha[r] + rs;
        }
        // P -> LDS (own wave's rows only; no barrier needed)
#pragma unroll
        for (int nt = 0; nt < 4; nt++)
#pragma unroll
            for (int r = 0; r < 4; r++)
                Ps[w * 16 + quad * 4 + r][nt * 16 + l15] = f2bf(sc[nt][r]);
        // rescale O
#pragma unroll
        for (int nt = 0; nt < 8; nt++)
#pragma unroll
            for (int r = 0; r < 4; r++) oacc[nt][r] *= alpha[r];
        // PV
        short8 pa0 = *(const short8*)&Ps[w * 16 + l15][quad * 8];
        short8 pa1 = *(const short8*)&Ps[w * 16 + l15][32 + quad * 8];
#pragma unroll
        for (int nt = 0; nt < 8; nt++) {
            short8 vf0 = *(const short8*)&Vt[nt * 16 + l15][quad * 8];
            short8 vf1 = *(const short8*)&Vt[nt * 16 + l15][32 + quad * 8];
            oacc[nt] = __builtin_amdgcn_mfma_f32_16x16x32_bf16(pa0, vf0, oacc[nt], 0, 0, 0);
            oacc[nt] = __builtin_amdgcn_mfma_f32_16x16x32_bf16(pa1, vf1, oacc[nt], 0, 0, 0);
        }
    }
    // epilogue: normalized partial O + (m,l)
#pragma unroll
    for (int r = 0; r < 4; r++) {
        float inv = 1.0f / l_r[r];
        size_t grow = qrow0 + w * 16 + quad * 4 + r;
        float* dst = opart + ((size_t)half * ROWS + grow) * KVE + h * 128;
#pragma unroll
        for (int nt = 0; nt < 8; nt++)
            dst[nt * 16 + l15] = oacc[nt][r] * inv;
        if (l15 == 0) {
            float* ml = mlbuf + (((size_t)half * ROWS + grow) * H + h) * 2;
            ml[0] = m_r[r];
            ml[1] = l_r[r];
        }
    }
}

// ---------------------------------------------------------------------------
// Partial combine + LayerNorm + RMSNorm + int8 quant (exact bf16 out)
// One block per row (512 cols, 2/thread). head = tid>>6.
// ---------------------------------------------------------------------------
__global__ __launch_bounds__(256) void ln_combine_kernel(
    const float* __restrict__ opart, const float* __restrict__ mlbuf,
    const float* __restrict__ gamma, const float* __restrict__ beta,
    short* __restrict__ xq, float* __restrict__ dqv)
{
    int row = blockIdx.x, tid = threadIdx.x;
    int h = tid >> 6;
    const float* ml0 = mlbuf + ((size_t)row * H + h) * 2;
    const float* ml1 = mlbuf + (((size_t)ROWS + row) * H + h) * 2;
    float m1 = ml0[0], l1v = ml0[1], m2 = ml1[0], l2v = ml1[1];
    float M = fmaxf(m1, m2);
    float w1 = l1v * __expf(m1 - M), w2 = l2v * __expf(m2 - M);
    float winv = 1.0f / (w1 + w2);
    w1 *= winv; w2 *= winv;
    float2 o1 = *(const float2*)(opart + (size_t)row * KVE + tid * 2);
    float2 o2 = *(const float2*)(opart + ((size_t)ROWS + row) * KVE + tid * 2);
    float vx = o1.x * w1 + o2.x * w2;
    float vy = o1.y * w1 + o2.y * w2;

    float s = vx + vy, ss = vx * vx + vy * vy;
#pragma unroll
    for (int o = 32; o; o >>= 1) { s += __shfl_xor(s, o); ss += __shfl_xor(ss, o); }
    __shared__ float r1[4], r2[4];
    int lane = tid & 63, wv = tid >> 6;
    if (!lane) { r1[wv] = s; r2[wv] = ss; }
    __syncthreads();
    float stot = r1[0] + r1[1] + r1[2] + r1[3];
    float sstot = r2[0] + r2[1] + r2[2] + r2[3];
    float mu = stot * (1.0f / KVE);
    float var = fmaxf(sstot * (1.0f / KVE) - mu * mu, 0.0f);
    float inv = rsqrtf(var + 1e-5f);
    float2 g = *(const float2*)(gamma + tid * 2);
    float2 be = *(const float2*)(beta + tid * 2);
    float y0 = (vx - mu) * inv * g.x + be.x;
    float y1 = (vy - mu) * inv * g.y + be.y;
    float sy = y0 * y0 + y1 * y1;
    float am = fmaxf(fabsf(y0), fabsf(y1));
#pragma unroll
    for (int o = 32; o; o >>= 1) { sy += __shfl_xor(sy, o); am = fmaxf(am, __shfl_xor(am, o)); }
    __syncthreads();
    if (!lane) { r1[wv] = sy; r2[wv] = am; }
    __syncthreads();
    float sytot = r1[0] + r1[1] + r1[2] + r1[3];
    float amax = fmaxf(fmaxf(r2[0], r2[1]), fmaxf(r2[2], r2[3]));
    float rms = rsqrtf(sytot * (1.0f / KVE) + 1e-6f);
    float cl = fmaxf(amax * rms, 1e-5f);
    float kf = rms * (127.0f / cl);
    int q0 = max(-128, min(127, (int)rintf(y0 * kf)));
    int q1 = max(-128, min(127, (int)rintf(y1 * kf)));
    xq[(size_t)row * KVE + tid * 2]     = f2bf((float)q0);
    xq[(size_t)row * KVE + tid * 2 + 1] = f2bf((float)q1);
    if (!tid) dqv[row] = cl * (1.0f / 127.0f);
}

// ---------------------------------------------------------------------------
extern "C" void kernel_launch(void* const* d_in, const int* in_sizes, int n_in,
                              void* d_out, int out_size, void* d_ws, size_t ws_size,
                              hipStream_t stream)
{
    const float* query = (const float*)d_in[0];
    const float* key   = (const float*)d_in[1];
    const float* value = (const float*)d_in[2];
    const float* q_w   = (const float*)d_in[3];
    const float* k_w   = (const float*)d_in[4];
    const float* v_w   = (const float*)d_in[5];
    const float* out_w = (const float*)d_in[6];
    const float* ln_g  = (const float*)d_in[7];
    const float* ln_b  = (const float*)d_in[8];
    float* out = (float*)d_out;

    // workspace carve (xq slice 2 aliases opart: dead before attn writes it)
    char* p = (char*)d_ws;
    float* stats = (float*)p;  p += 256;
    short* wq_q = (short*)p;   p += (size_t)1024 * 1024 * 2;
    short* wq_k = (short*)p;   p += (size_t)512 * 1024 * 2;
    short* wq_v = (short*)p;   p += (size_t)512 * 1024 * 2;
    short* wq_o = (short*)p;   p += (size_t)1024 * 512 * 2;
    short* xq01 = (short*)p;   p += (size_t)2 * ROWS * E * 2;
    float* dqv  = (float*)p;   p += (size_t)3 * ROWS * 4;
    short* qb   = (short*)p;   p += (size_t)ROWS * E * 2;
    short* kb   = (short*)p;   p += (size_t)ROWS * KVE * 2;
    short* vb   = (short*)p;   p += (size_t)ROWS * KVE * 2;
    float* opart = (float*)p;  p += (size_t)2 * ROWS * KVE * 4;
    float* mlbuf = (float*)p;  p += (size_t)2 * ROWS * H * 2 * 4;
    short* xq2  = (short*)opart;  // alias: 16 MB, dead before attn runs
    if ((size_t)(p - (char*)d_ws) > ws_size) return;

    dim3 blk(256);
    hipMemsetAsync(stats, 0, 256, stream);
    wstats_kernel<<<dim3(64, 4), blk, 0, stream>>>(q_w, k_w, v_w, out_w,
        1024 * 1024, 512 * 1024, 512 * 1024, 1024 * 512, stats);
    wquant_kernel<<<dim3(64, 4), blk, 0, stream>>>(q_w, k_w, v_w, out_w,
        1024 * 1024, 512 * 1024, 512 * 1024, 1024 * 512, stats, wq_q, wq_k, wq_v, wq_o);

    aquant3_kernel<<<dim3(ROWS, 3), blk, 0, stream>>>(query, key, value, xq01, xq2, dqv);
    gemm_qkv<<<dim3(1024), blk, 0, stream>>>(xq01, xq2, wq_q, wq_k, wq_v,
        dqv, stats, qb, kb, vb);

    attn_mfma<<<dim3(SEQ / 64, H, B_ * 2), blk, 0, stream>>>(qb, kb, vb, opart, mlbuf);

    ln_combine_kernel<<<ROWS, blk, 0, stream>>>(opart, mlbuf, ln_g, ln_b, xq01, dqv);
    gemm_out<<<dim3(8, 64), blk, 0, stream>>>(xq01, wq_o, dqv, stats, out);
}

// Round 5
// 350.122 us; speedup vs baseline: 5.4954x; 1.0525x over previous
//
#include <hip/hip_runtime.h>
#include <cstdint>
#include <cstddef>

// Problem constants
constexpr int B_   = 4;
constexpr int SEQ  = 2048;
constexpr int E    = 1024;   // embed dim
constexpr int KVE  = 512;    // kv embed dim
constexpr int H    = 4;      // kv heads
constexpr int ROWS = B_ * SEQ;   // 8192 tokens

typedef short short8  __attribute__((ext_vector_type(8)));
typedef short short4v __attribute__((ext_vector_type(4)));
typedef float floatx4 __attribute__((ext_vector_type(4)));

__device__ inline short f2bf(float f) {   // RNE float->bf16
    uint32_t u = __builtin_bit_cast(uint32_t, f);
    u = (u + 0x7fff + ((u >> 16) & 1)) >> 16;
    return (short)u;
}
__device__ inline float bf2f(short s) {
    return __builtin_bit_cast(float, (uint32_t)(uint16_t)s << 16);
}
__device__ inline void gl_lds16(const void* g, void* l) {
    __builtin_amdgcn_global_load_lds(
        (const __attribute__((address_space(1))) unsigned int*)g,
        (__attribute__((address_space(3))) unsigned int*)l, 16, 0, 0);
}

// ---------------------------------------------------------------------------
// Weight stats: per-matrix sum(w) and sum(|w|)
// ---------------------------------------------------------------------------
__global__ __launch_bounds__(256) void wstats_kernel(
    const float* __restrict__ w0, const float* __restrict__ w1,
    const float* __restrict__ w2, const float* __restrict__ w3,
    int n0, int n1, int n2, int n3, float* __restrict__ stats)
{
    int m = blockIdx.y;
    const float* w = (m == 0) ? w0 : (m == 1) ? w1 : (m == 2) ? w2 : w3;
    int n = (m == 0) ? n0 : (m == 1) ? n1 : (m == 2) ? n2 : n3;
    float s = 0.f, sa = 0.f;
    for (int i = blockIdx.x * 256 + threadIdx.x; i < n; i += gridDim.x * 256) {
        float x = w[i];
        s += x; sa += fabsf(x);
    }
#pragma unroll
    for (int o = 32; o; o >>= 1) { s += __shfl_xor(s, o); sa += __shfl_xor(sa, o); }
    __shared__ float ls[4], lsa[4];
    int lane = threadIdx.x & 63, wv = threadIdx.x >> 6;
    if (!lane) { ls[wv] = s; lsa[wv] = sa; }
    __syncthreads();
    if (!threadIdx.x) {
        atomicAdd(&stats[2 * m],     ls[0] + ls[1] + ls[2] + ls[3]);
        atomicAdd(&stats[2 * m + 1], lsa[0] + lsa[1] + lsa[2] + lsa[3]);
    }
}

// ---------------------------------------------------------------------------
// Weight ternary quant -> bf16 {-1,0,+1}
// ---------------------------------------------------------------------------
__global__ __launch_bounds__(256) void wquant_kernel(
    const float* __restrict__ w0, const float* __restrict__ w1,
    const float* __restrict__ w2, const float* __restrict__ w3,
    int n0, int n1, int n2, int n3, const float* __restrict__ stats,
    short* __restrict__ o0, short* __restrict__ o1,
    short* __restrict__ o2, short* __restrict__ o3)
{
    int m = blockIdx.y;
    const float* w = (m == 0) ? w0 : (m == 1) ? w1 : (m == 2) ? w2 : w3;
    int n = (m == 0) ? n0 : (m == 1) ? n1 : (m == 2) ? n2 : n3;
    short* o = (m == 0) ? o0 : (m == 1) ? o1 : (m == 2) ? o2 : o3;
    float e = stats[2 * m] / (float)n;
    int n4 = n >> 2;
    for (int i = blockIdx.x * 256 + threadIdx.x; i < n4; i += gridDim.x * 256) {
        float4 x = ((const float4*)w)[i];
        short4v q;
        q.x = (x.x > e) ? (short)0x3F80 : (x.x < e) ? (short)0xBF80 : (short)0;
        q.y = (x.y > e) ? (short)0x3F80 : (x.y < e) ? (short)0xBF80 : (short)0;
        q.z = (x.z > e) ? (short)0x3F80 : (x.z < e) ? (short)0xBF80 : (short)0;
        q.w = (x.w > e) ? (short)0x3F80 : (x.w < e) ? (short)0xBF80 : (short)0;
        *(short4v*)(o + ((size_t)i << 2)) = q;
    }
}

// ---------------------------------------------------------------------------
// Activation quant (fused q/k/v): RMSNorm -> int8 stored as exact bf16
// ---------------------------------------------------------------------------
__global__ __launch_bounds__(256) void aquant3_kernel(
    const float* __restrict__ q, const float* __restrict__ k,
    const float* __restrict__ vv, short* __restrict__ xq01,
    short* __restrict__ xq2, float* __restrict__ dqv)
{
    int z = blockIdx.y;
    const float* x = (z == 0) ? q : (z == 1) ? k : vv;
    short* xq = (z == 2) ? xq2 : xq01 + (size_t)z * ROWS * E;
    float* dq = dqv + (size_t)z * ROWS;
    int tid = threadIdx.x;
    size_t base = (size_t)blockIdx.x * E;
    float4 t = *(const float4*)(x + base + tid * 4);
    float v[4] = { t.x, t.y, t.z, t.w };
    float ss = 0.f, am = 0.f;
#pragma unroll
    for (int i = 0; i < 4; i++) { ss += v[i] * v[i]; am = fmaxf(am, fabsf(v[i])); }
#pragma unroll
    for (int o = 32; o; o >>= 1) { ss += __shfl_xor(ss, o); am = fmaxf(am, __shfl_xor(am, o)); }
    __shared__ float l1[4], l2[4];
    int lane = tid & 63, wv = tid >> 6;
    if (!lane) { l1[wv] = ss; l2[wv] = am; }
    __syncthreads();
    ss = l1[0] + l1[1] + l1[2] + l1[3];
    am = fmaxf(fmaxf(l2[0], l2[1]), fmaxf(l2[2], l2[3]));
    float rms = rsqrtf(ss * (1.0f / E) + 1e-6f);
    float cl  = fmaxf(am * rms, 1e-5f);
    float kf  = rms * (127.0f / cl);
    short4v pk;
#pragma unroll
    for (int i = 0; i < 4; i++) {
        int qi = (int)rintf(v[i] * kf);
        qi = max(-128, min(127, qi));
        pk[i] = f2bf((float)qi);
    }
    *(short4v*)(xq + base + tid * 4) = pk;
    if (!tid) dq[blockIdx.x] = cl * (1.0f / 127.0f);
}

// ---------------------------------------------------------------------------
// bf16 MFMA GEMM body (bit-exact). 128x128 tile, BK=32, global_load_lds w16.
// ---------------------------------------------------------------------------
template <bool F32OUT>
__device__ inline void gemm_body(
    const short* __restrict__ A, const short* __restrict__ W,
    const float* __restrict__ dqv, float sw, void* __restrict__ Cout,
    int O, int K, short* As, short* Ws, size_t row0, size_t c0)
{
    int tid = threadIdx.x;
    int w = tid >> 6, lane = tid & 63;
    int quad = lane >> 4, l15 = lane & 15;
    int mbase = (w & 1) * 64, nbase = (w >> 1) * 64;

    floatx4 acc[4][4];
#pragma unroll
    for (int i = 0; i < 4; i++)
#pragma unroll
        for (int j = 0; j < 4; j++) acc[i][j] = (floatx4){0.f, 0.f, 0.f, 0.f};

    int cA0 = tid, cA1 = tid + 256;
    int rA0 = cA0 >> 2, gA0 = (cA0 & 3) ^ (rA0 & 3);
    int rA1 = cA1 >> 2, gA1 = (cA1 & 3) ^ (rA1 & 3);
    const short* Ag0 = A + (row0 + rA0) * K + gA0 * 8;
    const short* Ag1 = A + (row0 + rA1) * K + gA1 * 8;
    const short* Wg0 = W + (c0 + rA0) * K + gA0 * 8;
    const short* Wg1 = W + (c0 + rA1) * K + gA1 * 8;
    short* lA0 = As + cA0 * 8;  short* lA1 = As + cA1 * 8;
    short* lW0 = Ws + cA0 * 8;  short* lW1 = Ws + cA1 * 8;

    for (int kt = 0; kt < K; kt += 32) {
        __syncthreads();
        gl_lds16(Ag0 + kt, lA0);
        gl_lds16(Ag1 + kt, lA1);
        gl_lds16(Wg0 + kt, lW0);
        gl_lds16(Wg1 + kt, lW1);
        __syncthreads();
        short8 af[4], bfr[4];
#pragma unroll
        for (int mt = 0; mt < 4; mt++) {
            int row = mbase + mt * 16 + l15;
            int pos = quad ^ (row & 3);
            af[mt] = *(const short8*)(As + row * 32 + pos * 8);
        }
#pragma unroll
        for (int nt = 0; nt < 4; nt++) {
            int row = nbase + nt * 16 + l15;
            int pos = quad ^ (row & 3);
            bfr[nt] = *(const short8*)(Ws + row * 32 + pos * 8);
        }
#pragma unroll
        for (int mt = 0; mt < 4; mt++)
#pragma unroll
            for (int nt = 0; nt < 4; nt++)
                acc[mt][nt] = __builtin_amdgcn_mfma_f32_16x16x32_bf16(
                    af[mt], bfr[nt], acc[mt][nt], 0, 0, 0);
    }

#pragma unroll
    for (int mt = 0; mt < 4; mt++) {
#pragma unroll
        for (int r = 0; r < 4; r++) {
            size_t grow = row0 + mbase + mt * 16 + quad * 4 + r;
            float scv = sw * dqv[grow];
#pragma unroll
            for (int nt = 0; nt < 4; nt++) {
                size_t gcol = c0 + nbase + nt * 16 + l15;
                float v = acc[mt][nt][r] * scv;
                if constexpr (F32OUT) ((float*)Cout)[grow * O + gcol] = v;
                else                  ((short*)Cout)[grow * O + gcol] = f2bf(v);
            }
        }
    }
}

// Batched QKV GEMM: flat 1024-block grid (512 q / 256 k / 256 v tiles).
__global__ __launch_bounds__(256) void gemm_qkv(
    const short* __restrict__ xq01, const short* __restrict__ xq2,
    const short* __restrict__ wq_q, const short* __restrict__ wq_k,
    const short* __restrict__ wq_v, const float* __restrict__ dqv,
    const float* __restrict__ stats,
    short* __restrict__ qb, short* __restrict__ kb, short* __restrict__ vb)
{
    __shared__ short As[128 * 32];
    __shared__ short Ws[128 * 32];
    int id = blockIdx.x;
    int z, bx, by;
    if (id < 512)      { z = 0; bx = id & 7; by = id >> 3; }
    else if (id < 768) { z = 1; int t = id - 512; bx = t & 3; by = t >> 2; }
    else               { z = 2; int t = id - 768; bx = t & 3; by = t >> 2; }
    int O = z ? KVE : E;
    const short* A = (z == 0) ? xq01 : (z == 1) ? xq01 + (size_t)ROWS * E : xq2;
    const short* W = (z == 0) ? wq_q : (z == 1) ? wq_k : wq_v;
    short* outp = (z == 0) ? qb : (z == 1) ? kb : vb;
    float sw = stats[2 * z + 1] / (float)(O * E);
    gemm_body<false>(A, W, dqv + (size_t)z * ROWS, sw, outp, O, E, As, Ws,
                     (size_t)by * 128, (size_t)bx * 128);
}

// Output GEMM (fp32 out, K=512)
__global__ __launch_bounds__(256) void gemm_out(
    const short* __restrict__ A, const short* __restrict__ W,
    const float* __restrict__ dqv, const float* __restrict__ stats,
    float* __restrict__ Cout)
{
    __shared__ short As[128 * 32];
    __shared__ short Ws[128 * 32];
    float sw = stats[7] / (float)(E * KVE);
    gemm_body<true>(A, W, dqv, sw, Cout, E, KVE, As, Ws,
                    (size_t)blockIdx.y * 128, (size_t)blockIdx.x * 128);
}

// ---------------------------------------------------------------------------
// MFMA flash attention v4: S^T orientation (K*Q^T) -> per-lane scalar softmax
// state, 2 shuffles per reduction instead of 32, packed b64 P-writes.
// 2-way KV split, reg-prefetch, Q staged via Ks. Grid (SEQ/64, H, B*2).
// ---------------------------------------------------------------------------
__global__ __launch_bounds__(256, 3) void attn_mfma(
    const short* __restrict__ qb, const short* __restrict__ kb,
    const short* __restrict__ vb, float* __restrict__ opart,
    float* __restrict__ mlbuf)
{
    __shared__ short Ks[64][140];
    __shared__ short Vt[128][76];
    __shared__ short Ps[64][76];
    int tid = threadIdx.x;
    int w = tid >> 6, lane = tid & 63, quad = lane >> 4, l15 = lane & 15;
    int blk = blockIdx.x, h = blockIdx.y;
    int b = blockIdx.z >> 1, half = blockIdx.z & 1;
    size_t qrow0 = (size_t)(b * SEQ + blk * 64);
    size_t sbase = (size_t)(b * SEQ + half * (SEQ / 2));

    int sK = tid >> 2, cK = tid & 3;          // K/Q staging: row, 32-col chunk
    int sV = (tid & 15) * 4, dV = tid >> 4;   // V staging: 4 rows, 8-col chunk

    // ---- prefetch KV tile 0 into registers (latency hidden by Q staging)
    short8 kreg[4], vreg[4];
    {
        const short* ksrc = kb + (sbase + sK) * KVE + h * 128 + cK * 32;
#pragma unroll
        for (int j = 0; j < 4; j++) kreg[j] = *(const short8*)(ksrc + j * 8);
        const short* vsrc = vb + (sbase + sV) * KVE + h * 128 + dV * 8;
#pragma unroll
        for (int j = 0; j < 4; j++) vreg[j] = *(const short8*)(vsrc + j * KVE);
    }

    // ---- stage Q via Ks: sum grouped head pair, fold 1/(scale^2) = 1/128
    {
        const short* src = qb + (qrow0 + sK) * E + h * 256 + cK * 32;
#pragma unroll
        for (int j = 0; j < 4; j++) {
            short8 a  = *(const short8*)(src + j * 8);
            short8 b2 = *(const short8*)(src + 128 + j * 8);
            short8 o;
#pragma unroll
            for (int e = 0; e < 8; e++)
                o[e] = f2bf((bf2f(a[e]) + bf2f(b2[e])) * (1.0f / 128.0f));
            *(short8*)&Ks[sK][cK * 32 + j * 8] = o;
        }
    }
    __syncthreads();
    // qa = B-frag (Q^T): lane supplies col q = w*16+l15, k-chunk quad*8+j
    short8 qa[4];
#pragma unroll
    for (int ks = 0; ks < 4; ks++)
        qa[ks] = *(const short8*)&Ks[w * 16 + l15][ks * 32 + quad * 8];

    // O^T accumulator: oacc[dt] holds O^T[dt*16+quad*4+r][q=w*16+l15]
    floatx4 oacc[8];
#pragma unroll
    for (int i = 0; i < 8; i++) oacc[i] = (floatx4){0.f, 0.f, 0.f, 0.f};
    float m_s = -1e30f, l_s = 0.f;   // per-lane scalars (q = w*16+l15)

    for (int st = 0; st < SEQ / 128; st++) {
        __syncthreads();   // prior readers of Ks/Vt done (incl. qa extraction)
        // commit prefetched K tile
#pragma unroll
        for (int j = 0; j < 4; j++)
            *(short8*)&Ks[sK][cK * 32 + j * 8] = kreg[j];
        // commit prefetched V tile (transposed)
#pragma unroll
        for (int i = 0; i < 8; i++) {
            short4v vv = { vreg[0][i], vreg[1][i], vreg[2][i], vreg[3][i] };
            *(short4v*)&Vt[dV * 8 + i][sV] = vv;
        }
        // issue next tile's global loads (hidden behind this tile's compute)
        if (st + 1 < SEQ / 128) {
            size_t srow0 = sbase + (size_t)(st + 1) * 64;
            const short* ksrc = kb + (srow0 + sK) * KVE + h * 128 + cK * 32;
#pragma unroll
            for (int j = 0; j < 4; j++) kreg[j] = *(const short8*)(ksrc + j * 8);
            const short* vsrc = vb + (srow0 + sV) * KVE + h * 128 + dV * 8;
#pragma unroll
            for (int j = 0; j < 4; j++) vreg[j] = *(const short8*)(vsrc + j * KVE);
        }
        __syncthreads();
        // S^T = K * Q^T: sc[nt][r] = S[q=w*16+l15][key = nt*16+quad*4+r]
        floatx4 sc[4];
#pragma unroll
        for (int nt = 0; nt < 4; nt++) {
            floatx4 a = (floatx4){0.f, 0.f, 0.f, 0.f};
#pragma unroll
            for (int ks = 0; ks < 4; ks++) {
                short8 kf = *(const short8*)&Ks[nt * 16 + l15][ks * 32 + quad * 8];
                a = __builtin_amdgcn_mfma_f32_16x16x32_bf16(kf, qa[ks], a, 0, 0, 0);
            }
            sc[nt] = a;
        }
        // online softmax over keys: 15 in-reg + 2 shuffles (all keys per q)
        float mx = sc[0][0];
#pragma unroll
        for (int nt = 0; nt < 4; nt++)
#pragma unroll
            for (int r = 0; r < 4; r++) mx = fmaxf(mx, sc[nt][r]);
        mx = fmaxf(mx, __shfl_xor(mx, 16));
        mx = fmaxf(mx, __shfl_xor(mx, 32));
        float nm = fmaxf(m_s, mx);
        float alpha = __expf(m_s - nm);
        m_s = nm;
        float rs = 0.f;
#pragma unroll
        for (int nt = 0; nt < 4; nt++)
#pragma unroll
            for (int r = 0; r < 4; r++) {
                float p = __expf(sc[nt][r] - nm);
                sc[nt][r] = p;
                rs += p;
            }
        rs += __shfl_xor(rs, 16);
        rs += __shfl_xor(rs, 32);
        l_s = l_s * alpha + rs;
        // P -> LDS, packed b64 (row q = w*16+l15, keys nt*16+quad*4..+3)
#pragma unroll
        for (int nt = 0; nt < 4; nt++) {
            short4v pp = { f2bf(sc[nt][0]), f2bf(sc[nt][1]),
                           f2bf(sc[nt][2]), f2bf(sc[nt][3]) };
            *(short4v*)&Ps[w * 16 + l15][nt * 16 + quad * 4] = pp;
        }
        // rescale O^T (scalar alpha per lane)
#pragma unroll
        for (int dt = 0; dt < 8; dt++)
#pragma unroll
            for (int r = 0; r < 4; r++) oacc[dt][r] *= alpha;
        // PV: O^T = V^T * P^T.  A = Vt-frag, B = P^T-frag (own wave's rows)
        short8 pb0 = *(const short8*)&Ps[w * 16 + l15][quad * 8];
        short8 pb1 = *(const short8*)&Ps[w * 16 + l15][32 + quad * 8];
#pragma unroll
        for (int dt = 0; dt < 8; dt++) {
            short8 vf0 = *(const short8*)&Vt[dt * 16 + l15][quad * 8];
            short8 vf1 = *(const short8*)&Vt[dt * 16 + l15][32 + quad * 8];
            oacc[dt] = __builtin_amdgcn_mfma_f32_16x16x32_bf16(vf0, pb0, oacc[dt], 0, 0, 0);
            oacc[dt] = __builtin_amdgcn_mfma_f32_16x16x32_bf16(vf1, pb1, oacc[dt], 0, 0, 0);
        }
    }
    // epilogue: normalized partial O + (m,l);  lane owns q = w*16+l15,
    // d = dt*16 + quad*4 + r  -> 8 float4 stores
    {
        float inv = 1.0f / l_s;
        size_t grow = qrow0 + w * 16 + l15;
        float* dst = opart + ((size_t)half * ROWS + grow) * KVE + h * 128;
#pragma unroll
        for (int dt = 0; dt < 8; dt++) {
            float4 o4 = { oacc[dt][0] * inv, oacc[dt][1] * inv,
                          oacc[dt][2] * inv, oacc[dt][3] * inv };
            *(float4*)(dst + dt * 16 + quad * 4) = o4;
        }
        if (quad == 0) {
            float* ml = mlbuf + (((size_t)half * ROWS + grow) * H + h) * 2;
            ml[0] = m_s;
            ml[1] = l_s;
        }
    }
}

// ---------------------------------------------------------------------------
// Partial combine + LayerNorm + RMSNorm + int8 quant (exact bf16 out)
// One block per row (512 cols, 2/thread). head = tid>>6.
// ---------------------------------------------------------------------------
__global__ __launch_bounds__(256) void ln_combine_kernel(
    const float* __restrict__ opart, const float* __restrict__ mlbuf,
    const float* __restrict__ gamma, const float* __restrict__ beta,
    short* __restrict__ xq, float* __restrict__ dqv)
{
    int row = blockIdx.x, tid = threadIdx.x;
    int h = tid >> 6;
    const float* ml0 = mlbuf + ((size_t)row * H + h) * 2;
    const float* ml1 = mlbuf + (((size_t)ROWS + row) * H + h) * 2;
    float m1 = ml0[0], l1v = ml0[1], m2 = ml1[0], l2v = ml1[1];
    float M = fmaxf(m1, m2);
    float w1 = l1v * __expf(m1 - M), w2 = l2v * __expf(m2 - M);
    float winv = 1.0f / (w1 + w2);
    w1 *= winv; w2 *= winv;
    float2 o1 = *(const float2*)(opart + (size_t)row * KVE + tid * 2);
    float2 o2 = *(const float2*)(opart + ((size_t)ROWS + row) * KVE + tid * 2);
    float vx = o1.x * w1 + o2.x * w2;
    float vy = o1.y * w1 + o2.y * w2;

    float s = vx + vy, ss = vx * vx + vy * vy;
#pragma unroll
    for (int o = 32; o; o >>= 1) { s += __shfl_xor(s, o); ss += __shfl_xor(ss, o); }
    __shared__ float r1[4], r2[4];
    int lane = tid & 63, wv = tid >> 6;
    if (!lane) { r1[wv] = s; r2[wv] = ss; }
    __syncthreads();
    float stot = r1[0] + r1[1] + r1[2] + r1[3];
    float sstot = r2[0] + r2[1] + r2[2] + r2[3];
    float mu = stot * (1.0f / KVE);
    float var = fmaxf(sstot * (1.0f / KVE) - mu * mu, 0.0f);
    float inv = rsqrtf(var + 1e-5f);
    float2 g = *(const float2*)(gamma + tid * 2);
    float2 be = *(const float2*)(beta + tid * 2);
    float y0 = (vx - mu) * inv * g.x + be.x;
    float y1 = (vy - mu) * inv * g.y + be.y;
    float sy = y0 * y0 + y1 * y1;
    float am = fmaxf(fabsf(y0), fabsf(y1));
#pragma unroll
    for (int o = 32; o; o >>= 1) { sy += __shfl_xor(sy, o); am = fmaxf(am, __shfl_xor(am, o)); }
    __syncthreads();
    if (!lane) { r1[wv] = sy; r2[wv] = am; }
    __syncthreads();
    float sytot = r1[0] + r1[1] + r1[2] + r1[3];
    float amax = fmaxf(fmaxf(r2[0], r2[1]), fmaxf(r2[2], r2[3]));
    float rms = rsqrtf(sytot * (1.0f / KVE) + 1e-6f);
    float cl = fmaxf(amax * rms, 1e-5f);
    float kf = rms * (127.0f / cl);
    int q0 = max(-128, min(127, (int)rintf(y0 * kf)));
    int q1 = max(-128, min(127, (int)rintf(y1 * kf)));
    xq[(size_t)row * KVE + tid * 2]     = f2bf((float)q0);
    xq[(size_t)row * KVE + tid * 2 + 1] = f2bf((float)q1);
    if (!tid) dqv[row] = cl * (1.0f / 127.0f);
}

// ---------------------------------------------------------------------------
extern "C" void kernel_launch(void* const* d_in, const int* in_sizes, int n_in,
                              void* d_out, int out_size, void* d_ws, size_t ws_size,
                              hipStream_t stream)
{
    const float* query = (const float*)d_in[0];
    const float* key   = (const float*)d_in[1];
    const float* value = (const float*)d_in[2];
    const float* q_w   = (const float*)d_in[3];
    const float* k_w   = (const float*)d_in[4];
    const float* v_w   = (const float*)d_in[5];
    const float* out_w = (const float*)d_in[6];
    const float* ln_g  = (const float*)d_in[7];
    const float* ln_b  = (const float*)d_in[8];
    float* out = (float*)d_out;

    // workspace carve (xq slice 2 aliases opart: dead before attn writes it)
    char* p = (char*)d_ws;
    float* stats = (float*)p;  p += 256;
    short* wq_q = (short*)p;   p += (size_t)1024 * 1024 * 2;
    short* wq_k = (short*)p;   p += (size_t)512 * 1024 * 2;
    short* wq_v = (short*)p;   p += (size_t)512 * 1024 * 2;
    short* wq_o = (short*)p;   p += (size_t)1024 * 512 * 2;
    short* xq01 = (short*)p;   p += (size_t)2 * ROWS * E * 2;
    float* dqv  = (float*)p;   p += (size_t)3 * ROWS * 4;
    short* qb   = (short*)p;   p += (size_t)ROWS * E * 2;
    short* kb   = (short*)p;   p += (size_t)ROWS * KVE * 2;
    short* vb   = (short*)p;   p += (size_t)ROWS * KVE * 2;
    float* opart = (float*)p;  p += (size_t)2 * ROWS * KVE * 4;
    float* mlbuf = (float*)p;  p += (size_t)2 * ROWS * H * 2 * 4;
    short* xq2  = (short*)opart;  // alias: 16 MB, dead before attn runs
    if ((size_t)(p - (char*)d_ws) > ws_size) return;

    dim3 blk(256);
    hipMemsetAsync(stats, 0, 256, stream);
    wstats_kernel<<<dim3(64, 4), blk, 0, stream>>>(q_w, k_w, v_w, out_w,
        1024 * 1024, 512 * 1024, 512 * 1024, 1024 * 512, stats);
    wquant_kernel<<<dim3(64, 4), blk, 0, stream>>>(q_w, k_w, v_w, out_w,
        1024 * 1024, 512 * 1024, 512 * 1024, 1024 * 512, stats, wq_q, wq_k, wq_v, wq_o);

    aquant3_kernel<<<dim3(ROWS, 3), blk, 0, stream>>>(query, key, value, xq01, xq2, dqv);
    gemm_qkv<<<dim3(1024), blk, 0, stream>>>(xq01, xq2, wq_q, wq_k, wq_v,
        dqv, stats, qb, kb, vb);

    attn_mfma<<<dim3(SEQ / 64, H, B_ * 2), blk, 0, stream>>>(qb, kb, vb, opart, mlbuf);

    ln_combine_kernel<<<ROWS, blk, 0, stream>>>(opart, mlbuf, ln_g, ln_b, xq01, dqv);
    gemm_out<<<dim3(8, 64), blk, 0, stream>>>(xq01, wq_o, dqv, stats, out);
}